// Round 11
// baseline (559.168 us; speedup 1.0000x reference)
//
#include <hip/hip_runtime.h>
#include <hip/hip_bf16.h>

typedef __bf16 bf16;
typedef __bf16 bf16x4 __attribute__((ext_vector_type(4)));
typedef __bf16 bf16x8 __attribute__((ext_vector_type(8)));
typedef float  f32x4  __attribute__((ext_vector_type(4)));

#define NB 2
#define NN 256
#define DD 768
#define EE 8192
#define NPAIR 32640

__device__ inline float wred_sum(float v) {
#pragma unroll
  for (int o = 32; o > 0; o >>= 1) v += __shfl_down(v, o, 64);
  return v;
}

typedef const __attribute__((address_space(1))) void GASV;
typedef __attribute__((address_space(3))) void LASV;
__device__ __forceinline__ void async_cp16(const void* g, void* l) {
  __builtin_amdgcn_global_load_lds((GASV*)g, (LASV*)l, 16, 0, 0);
}

// ---- preamble: f32->bf16 converts + edge buckets + pair table, ONE launch ----
struct CJob { const float* s; bf16* d; int n; };
struct CJobs { CJob j[15]; };
__global__ __launch_bounds__(256) void preamble(
    CJobs jobs, const int* __restrict__ eidx, int* __restrict__ estart,
    int* __restrict__ bucket, int2* __restrict__ pairs)
{
  int by = blockIdx.y, t = threadIdx.x;
  if (by < 15) {
    const CJob jb = jobs.j[by];
    int nv = jb.n >> 2;
    for (int i = blockIdx.x * 256 + t; i < nv; i += gridDim.x * 256) {
      float4 v = ((const float4*)jb.s)[i];
      bf16x4 pk = { (bf16)v.x, (bf16)v.y, (bf16)v.z, (bf16)v.w };
      *(bf16x4*)(jb.d + 4 * i) = pk;
    }
  } else if (by == 15) {
    if (blockIdx.x != 0) return;
    __shared__ int tg[EE];   // 32 KB
    __shared__ int cnt[256];
    __shared__ int sst[257];
    cnt[t] = 0;
    for (int e = t; e < EE; e += 256) tg[e] = eidx[2 * e + 1];
    __syncthreads();
    for (int e = t; e < EE; e += 256) atomicAdd(&cnt[tg[e]], 1);
    __syncthreads();
    if (t == 0) { int s = 0; for (int i = 0; i < 256; ++i) { sst[i] = s; s += cnt[i]; } sst[256] = s; }
    __syncthreads();
    estart[t] = sst[t];
    if (t == 0) estart[256] = sst[256];
    cnt[t] = sst[t];
    __syncthreads();
    for (int e = t; e < EE; e += 256) {
      int p = atomicAdd(&cnt[tg[e]], 1);
      bucket[p] = e;
    }
  } else {
#pragma unroll
    for (int u = 0; u < 2; ++u) {
      int i = blockIdx.x + u * 128;
      if (i < 255) {
        int off = i * 255 - (i * (i - 1)) / 2;
        for (int j = i + 1 + t; j < NN; j += 256)
          pairs[off + (j - i - 1)] = make_int2(i, j);
      }
    }
  }
}

// GEMM core: one wave computes a 16x32 tile at (m0, n0). lane = tid&63.
__device__ __forceinline__ void lin_core(
    int m0, int n0, const bf16* __restrict__ X, const bf16* __restrict__ W,
    int ldw, int wofs, const float* __restrict__ bias, const float* __restrict__ addF,
    bf16* __restrict__ outB, float* __restrict__ outF, int N, int K, int act)
{
  int lane = threadIdx.x & 63, lr = lane & 15, lq = lane >> 4;
  const bf16* xrow = X + (size_t)(m0 + lr) * K;
  const bf16* wbase = W + (size_t)wofs;
  f32x4 acc[2] = {};
  for (int k = 0; k < K; k += 32) {
    bf16x8 a = *(const bf16x8*)(xrow + k + lq * 8);
    bf16x8 b0 = *(const bf16x8*)(wbase + (size_t)(n0 + lr) * ldw + k + lq * 8);
    bf16x8 b1 = *(const bf16x8*)(wbase + (size_t)(n0 + 16 + lr) * ldw + k + lq * 8);
    acc[0] = __builtin_amdgcn_mfma_f32_16x16x32_bf16(a, b0, acc[0], 0, 0, 0);
    acc[1] = __builtin_amdgcn_mfma_f32_16x16x32_bf16(a, b1, acc[1], 0, 0, 0);
  }
#pragma unroll
  for (int t = 0; t < 2; ++t) {
    int col = n0 + t * 16 + lr;
    float bv = bias ? bias[col] : 0.0f;
#pragma unroll
    for (int r = 0; r < 4; ++r) {
      int row = m0 + lq * 4 + r;
      size_t o = (size_t)row * N + col;
      float v = acc[t][r] + bv;
      if (addF) v += addF[o];
      if (act) v = fmaxf(v, 0.0f);
      if (outB) outB[o] = (bf16)v;
      if (outF) outF[o] = v;
    }
  }
}

__global__ __launch_bounds__(128) void linear_mfma(
    const bf16* __restrict__ X, const bf16* __restrict__ W, int ldw, int wofs,
    const float* __restrict__ bias, const float* __restrict__ addF,
    bf16* __restrict__ outB, float* __restrict__ outF,
    int N, int K, int act)
{
  int wave = threadIdx.x >> 6;
  lin_core((blockIdx.x * 2 + wave) * 16, blockIdx.y * 32,
           X, W, ldw, wofs, bias, addF, outB, outF, N, K, act);
}

// Two independent GEMMs in one launch; blockIdx.z picks the job.
struct LinJob {
  const bf16* X; const bf16* W; int ldw; int wofs;
  const float* bias; const float* addF; bf16* outB; float* outF;
  int N, K, act, gy;
};
__global__ __launch_bounds__(128) void linear_mfma2(LinJob j0, LinJob j1)
{
  LinJob j = blockIdx.z ? j1 : j0;
  if ((int)blockIdx.y >= j.gy) return;
  int wave = threadIdx.x >> 6;
  lin_core((blockIdx.x * 2 + wave) * 16, blockIdx.y * 32,
           j.X, j.W, j.ldw, j.wofs, j.bias, j.addF, j.outB, j.outF, j.N, j.K, j.act);
}

// GNN stage-1: self-linear (blocks 0..191) + edge aggregation (blocks 192..703)
__global__ __launch_bounds__(256) void gnn_stage1(
    const bf16* __restrict__ g, const bf16* __restrict__ ws, const float* __restrict__ bs,
    float* __restrict__ selfF,
    const float* __restrict__ ew, const int* __restrict__ eidx,
    const int* __restrict__ estart, const int* __restrict__ bucket, bf16* __restrict__ agg)
{
  int bid = blockIdx.x, t = threadIdx.x;
  if (bid < 192) {
    int wave = t >> 6;
    lin_core(((bid & 7) * 4 + wave) * 16, (bid >> 3) * 32,
             g, ws, 768, 0, bs, nullptr, nullptr, selfF, 768, 768, 0);
    return;
  }
  __shared__ int   ssrc[256];
  __shared__ float sw[256];
  int e0 = bid - 192;
  int tgt = e0 & 255, b = e0 >> 8;
  int s = estart[tgt], e = estart[tgt + 1];
  s = max(0, min(s, EE));
  e = max(s, min(e, EE));
  const bf16* gb = g + (size_t)b * NN * DD;
  float a0 = 0, a1 = 0, a2 = 0, a3 = 0;
  for (int base = s; base < e; base += 256) {
    int nchunk = min(256, e - base);
    if (t < nchunk) {
      int eid = bucket[base + t];
      eid = max(0, min(eid, EE - 1));
      ssrc[t] = eidx[2 * eid] & (NN - 1);
      sw[t] = ew[eid];
    }
    __syncthreads();
    if (t < 192) {
      for (int q = 0; q < nchunk; ++q) {
        float w = sw[q];
        bf16x4 v = *(const bf16x4*)(gb + (size_t)ssrc[q] * DD + 4 * t);
        a0 += w * (float)v[0]; a1 += w * (float)v[1];
        a2 += w * (float)v[2]; a3 += w * (float)v[3];
      }
    }
    __syncthreads();
  }
  if (t < 192) {
    bf16x4 o = { (bf16)a0, (bf16)a1, (bf16)a2, (bf16)a3 };
    *(bf16x4*)(agg + ((size_t)b * NN + tgt) * DD + 4 * t) = o;
  }
}

// GNN stage-2 FUSED: o = relu(agg@wn^T + bn + selfF); g = LN(o)*gm + bt.
// Block = 16 rows x full 768 cols; 4 waves; wave w covers cols w*192..+192
// (12 cf-tiles of 16 — R10 bug was acc[6]: half the cols never computed).
__global__ __launch_bounds__(256) void gnn_stage2(
    const bf16* __restrict__ agg, const bf16* __restrict__ wn, const float* __restrict__ bn,
    const float* __restrict__ selfF, const float* __restrict__ gm,
    const float* __restrict__ bt, bf16* __restrict__ gout)
{
  __shared__ float red[4][4][4][2];
  int tid = threadIdx.x;
  int wave = tid >> 6, lane = tid & 63, lr = lane & 15, lq = lane >> 4;
  int m0 = blockIdx.x * 16;
  const bf16* xrow = agg + (size_t)(m0 + lr) * 768;
  f32x4 acc[12] = {};
  for (int k = 0; k < 768; k += 32) {
    bf16x8 a = *(const bf16x8*)(xrow + k + lq * 8);
#pragma unroll
    for (int cf = 0; cf < 12; ++cf) {
      bf16x8 b = *(const bf16x8*)(wn + (size_t)(wave * 192 + cf * 16 + lr) * 768 + k + lq * 8);
      acc[cf] = __builtin_amdgcn_mfma_f32_16x16x32_bf16(a, b, acc[cf], 0, 0, 0);
    }
  }
  float v[12][4];
  float s[4] = {0, 0, 0, 0}, q[4] = {0, 0, 0, 0};
#pragma unroll
  for (int cf = 0; cf < 12; ++cf) {
    int col = wave * 192 + cf * 16 + lr;
    float bv = bn[col];
#pragma unroll
    for (int r = 0; r < 4; ++r) {
      int row = m0 + lq * 4 + r;
      float x = fmaxf(acc[cf][r] + bv + selfF[(size_t)row * 768 + col], 0.f);
      v[cf][r] = x;
      s[r] += x; q[r] += x * x;
    }
  }
#pragma unroll
  for (int r = 0; r < 4; ++r) {
#pragma unroll
    for (int m = 1; m < 16; m <<= 1) {
      s[r] += __shfl_xor(s[r], m, 64);
      q[r] += __shfl_xor(q[r], m, 64);
    }
  }
  if (lr == 0) {
#pragma unroll
    for (int r = 0; r < 4; ++r) { red[wave][lq][r][0] = s[r]; red[wave][lq][r][1] = q[r]; }
  }
  __syncthreads();
#pragma unroll
  for (int r = 0; r < 4; ++r) {
    float S = red[0][lq][r][0] + red[1][lq][r][0] + red[2][lq][r][0] + red[3][lq][r][0];
    float Q = red[0][lq][r][1] + red[1][lq][r][1] + red[2][lq][r][1] + red[3][lq][r][1];
    float mu = S * (1.0f / 768.0f);
    float var = Q * (1.0f / 768.0f) - mu * mu;
    float rstd = rsqrtf(var + 1e-5f);
    int row = m0 + lq * 4 + r;
#pragma unroll
    for (int cf = 0; cf < 12; ++cf) {
      int col = wave * 192 + cf * 16 + lr;
      gout[(size_t)row * 768 + col] = (bf16)(gm[col] * (v[cf][r] - mu) * rstd + bt[col]);
    }
  }
}

// grid (q=256, h=8, b=2); one block per (b,h,q) row.
__global__ __launch_bounds__(256) void attn_kernel(
    const bf16* __restrict__ qkv, float* __restrict__ aw, bf16* __restrict__ ctx)
{
  __shared__ float qs[96];
  __shared__ float ps[256];
  __shared__ float part[192];
  __shared__ float red[8];
  int qi = blockIdx.x, h = blockIdx.y, b = blockIdx.z, t = threadIdx.x;
  const bf16* qrow = qkv + ((size_t)(b * NN + qi)) * 2304 + h * 96;
  if (t < 96) qs[t] = (float)qrow[t];
  __syncthreads();
  const bf16* krow = qkv + ((size_t)(b * NN + t)) * 2304 + 768 + h * 96;
  float s = 0;
#pragma unroll
  for (int i = 0; i < 12; ++i) {
    bf16x8 kv = *(const bf16x8*)(krow + 8 * i);
#pragma unroll
    for (int j = 0; j < 8; ++j) s += qs[8 * i + j] * (float)kv[j];
  }
  s *= 0.10206207261596577f; // 1/sqrt(96)
  float wm = s;
#pragma unroll
  for (int o = 32; o > 0; o >>= 1) wm = fmaxf(wm, __shfl_down(wm, o, 64));
  if ((t & 63) == 0) red[t >> 6] = wm;
  __syncthreads();
  float MX = fmaxf(fmaxf(red[0], red[1]), fmaxf(red[2], red[3]));
  float e = expf(s - MX);
  float wsum = wred_sum(e);
  if ((t & 63) == 0) red[4 + (t >> 6)] = wsum;
  __syncthreads();
  float SUM = red[4] + red[5] + red[6] + red[7];
  float p = e / SUM;
  ps[t] = p;
  atomicAdd(&aw[((size_t)(b * NN + qi)) * NN + t], p * 0.125f);
  __syncthreads();
  if (t < 192) {
    int d = t % 96, half = t / 96;
    const bf16* vbase = qkv + (size_t)b * NN * 2304 + 1536 + h * 96 + d;
    float a0 = 0, a1 = 0, a2 = 0, a3 = 0;
    int k0 = half * 128;
    for (int k = k0; k < k0 + 128; k += 4) {
      a0 += ps[k]     * (float)vbase[(size_t)k * 2304];
      a1 += ps[k + 1] * (float)vbase[(size_t)(k + 1) * 2304];
      a2 += ps[k + 2] * (float)vbase[(size_t)(k + 2) * 2304];
      a3 += ps[k + 3] * (float)vbase[(size_t)(k + 3) * 2304];
    }
    part[t] = (a0 + a1) + (a2 + a3);
  }
  __syncthreads();
  if (t < 96)
    ctx[((size_t)(b * NN + qi)) * DD + h * 96 + t] = (bf16)(part[t] + part[t + 96]);
}

// oc softmax head (blocks 0..31) + ip sigmoid head (blocks 32..63), one launch.
__global__ __launch_bounds__(256) void small_heads(
    const bf16* __restrict__ hOC, const float* __restrict__ w3, const float* __restrict__ b3,
    float* __restrict__ outOC,
    const bf16* __restrict__ hIP, const float* __restrict__ w1, const float* __restrict__ b1,
    float* __restrict__ outIP)
{
  int t = threadIdx.x;
  int wave = t >> 6, lane = t & 63;
  if (blockIdx.x < 32) {
    __shared__ float sw3[8 * 384];
    for (int i = t; i < 8 * 384; i += 256) sw3[i] = w3[i];
    __syncthreads();
    int k0 = lane * 6;
#pragma unroll
    for (int i = 0; i < 4; ++i) {
      int r = blockIdx.x * 16 + wave * 4 + i;
      const bf16* hr = hOC + (size_t)r * 384;
      float hv[6];
#pragma unroll
      for (int j = 0; j < 6; ++j) hv[j] = (float)hr[k0 + j];
      float lg[8];
#pragma unroll
      for (int c = 0; c < 8; ++c) {
        float p = 0;
#pragma unroll
        for (int j = 0; j < 6; ++j) p += hv[j] * sw3[c * 384 + k0 + j];
        lg[c] = wred_sum(p);
      }
      if (lane == 0) {
        float mx = lg[0] + b3[0];
#pragma unroll
        for (int c = 0; c < 8; ++c) { lg[c] += b3[c]; mx = fmaxf(mx, lg[c]); }
        float ex[8], sum = 0;
#pragma unroll
        for (int c = 0; c < 8; ++c) { ex[c] = expf(lg[c] - mx); sum += ex[c]; }
        float inv = 1.0f / sum;
#pragma unroll
        for (int c = 0; c < 8; ++c) outOC[(size_t)r * 8 + c] = ex[c] * inv;
      }
    }
  } else {
    __shared__ float sw1[192];
    if (t < 192) sw1[t] = w1[t];
    __syncthreads();
    int k0 = lane * 3;
#pragma unroll
    for (int i = 0; i < 4; ++i) {
      int r = (blockIdx.x - 32) * 16 + wave * 4 + i;
      const bf16* hr = hIP + (size_t)r * 192;
      float p = (float)hr[k0] * sw1[k0] + (float)hr[k0 + 1] * sw1[k0 + 1]
              + (float)hr[k0 + 2] * sw1[k0 + 2];
      float s = wred_sum(p);
      if (lane == 0) outIP[r] = 1.0f / (1.0f + expf(-(s + b1[0])));
    }
  }
}

// Relation hidden GEMM + FUSED head partials (verified correct in R10:
// relation output passed through this path).
__global__ __launch_bounds__(256) void h2_gemm(
    const bf16* __restrict__ Af, const bf16* __restrict__ Bf,
    const bf16* __restrict__ w2, const float* __restrict__ b2,
    const float* __restrict__ w3, const int2* __restrict__ pairs,
    float* __restrict__ logP)
{
  __shared__ bf16x8 sh1[512];   // 8 KB  (128 rows x 4 planes)
  __shared__ bf16x8 sw2[768];   // 12 KB (192 rows x 4 planes)
  __shared__ int rA[128], rB[128];
  int tid = threadIdx.x;
  int r0 = blockIdx.x * 128;
  int bb = (r0 >= NPAIR) ? 1 : 0;   // tiles never straddle batches (32640%128==0)
  int n0 = blockIdx.y * 192;
  if (tid < 128) {
    int2 ij = pairs[r0 - bb * NPAIR + tid];
    rA[tid] = (bb * NN + ij.x) * DD;
    rB[tid] = (bb * NN + ij.y) * DD;
  }
  __syncthreads();
  int hrow = tid >> 1, hp = (tid & 1) * 2;
  const bf16* ar = Af + rA[hrow] + hp * 8;
  const bf16* br = Bf + rB[hrow] + hp * 8;
  int hslot = ((hrow >> 4) << 6) + (hp << 4) + (hrow & 15);
  int srow[3], spl[3];
#pragma unroll
  for (int q = 0; q < 3; ++q) {
    int a = q * 256 + tid;
    srow[q] = ((a >> 6) << 4) + (a & 15);
    spl[q] = (a >> 4) & 3;
  }
  int wave = tid >> 6, lane = tid & 63, lr = lane & 15, lq = lane >> 4;
  int wr = wave >> 1, wc = wave & 1;
  f32x4 acc[4][6] = {};
  for (int k0 = 0; k0 < 768; k0 += 32) {
#pragma unroll
    for (int q = 0; q < 3; ++q)
      async_cp16(w2 + (size_t)(n0 + srow[q]) * 768 + k0 + spl[q] * 8,
                 (char*)sw2 + (q * 256 + tid) * 16);
    bf16x8 a0 = *(const bf16x8*)(ar + k0);
    bf16x8 a1 = *(const bf16x8*)(ar + k0 + 8);
    bf16x8 b0 = *(const bf16x8*)(br + k0);
    bf16x8 b1 = *(const bf16x8*)(br + k0 + 8);
    bf16x8 h0, h1v;
#pragma unroll
    for (int j = 0; j < 8; ++j) {
      h0[j]  = (bf16)fmaxf((float)a0[j] + (float)b0[j], 0.f);
      h1v[j] = (bf16)fmaxf((float)a1[j] + (float)b1[j], 0.f);
    }
    sh1[hslot] = h0;
    sh1[hslot + 16] = h1v;
    __syncthreads();
    bf16x8 af[4], bfr[6];
#pragma unroll
    for (int rf = 0; rf < 4; ++rf)
      af[rf] = sh1[(wr * 4 + rf) * 64 + lq * 16 + lr];
#pragma unroll
    for (int cf = 0; cf < 6; ++cf)
      bfr[cf] = sw2[(wc * 6 + cf) * 64 + lq * 16 + lr];
#pragma unroll
    for (int rf = 0; rf < 4; ++rf)
#pragma unroll
      for (int cf = 0; cf < 6; ++cf)
        acc[rf][cf] = __builtin_amdgcn_mfma_f32_16x16x32_bf16(af[rf], bfr[cf], acc[rf][cf], 0, 0, 0);
    __syncthreads();   // also frees sh1/sw2 for epilogue reuse on last iter
  }
  // ---- fused relation head ----
  char* zone = (wave < 2) ? ((char*)sw2 + wave * 3328)
                          : ((char*)sh1 + (wave - 2) * 3328);
  bf16x8 w3f[3];
#pragma unroll
  for (int ks = 0; ks < 3; ++ks) {
    bf16x8 f = {};
    if (lr < 8) {
      const float* wsrc = w3 + lr * 384 + n0 + wc * 96 + ks * 32 + lq * 8;
#pragma unroll
      for (int j = 0; j < 8; ++j) f[j] = (bf16)wsrc[j];
    }
    w3f[ks] = f;
  }
  float* lp = logP + (size_t)((n0 >= 192 ? 2 : 0) + wc) * 65280 * 8;
  bf16* zb = (bf16*)zone;
#pragma unroll
  for (int rf = 0; rf < 4; ++rf) {
#pragma unroll
    for (int cf = 0; cf < 6; ++cf) {
      int col = n0 + wc * 96 + cf * 16 + lr;
      float bv2 = b2[col];
#pragma unroll
      for (int r = 0; r < 4; ++r)
        zb[(lq * 4 + r) * 104 + cf * 16 + lr] = (bf16)fmaxf(acc[rf][cf][r] + bv2, 0.f);
    }
    f32x4 lacc = {};
#pragma unroll
    for (int ks = 0; ks < 3; ++ks) {
      bf16x8 afr = *(const bf16x8*)(zone + lr * 208 + ks * 64 + lq * 16);
      lacc = __builtin_amdgcn_mfma_f32_16x16x32_bf16(afr, w3f[ks], lacc, 0, 0, 0);
    }
    if (lr < 8) {
#pragma unroll
      for (int r = 0; r < 4; ++r) {
        int grow = r0 + wr * 64 + rf * 16 + lq * 4 + r;
        lp[(size_t)grow * 8 + lr] = lacc[r];
      }
    }
  }
}

// Sum 4 logit partials + bias, softmax, write out_rel. Thread = one pair-row.
__global__ __launch_bounds__(256) void relsoftmax(
    const float* __restrict__ logP, const float* __restrict__ b3,
    float* __restrict__ out)
{
  int row = blockIdx.x * 256 + threadIdx.x;   // grid 255*256 = 65280
  float lg[8];
#pragma unroll
  for (int c = 0; c < 8; ++c) lg[c] = b3[c];
#pragma unroll
  for (int p = 0; p < 4; ++p) {
    const float* lp = logP + ((size_t)p * 65280 + row) * 8;
#pragma unroll
    for (int c = 0; c < 8; ++c) lg[c] += lp[c];
  }
  float mx = lg[0];
#pragma unroll
  for (int c = 1; c < 8; ++c) mx = fmaxf(mx, lg[c]);
  float ex[8], sum = 0;
#pragma unroll
  for (int c = 0; c < 8; ++c) { ex[c] = expf(lg[c] - mx); sum += ex[c]; }
  float inv = 1.0f / sum;
#pragma unroll
  for (int c = 0; c < 8; ++c) out[(size_t)row * 8 + c] = ex[c] * inv;
}

extern "C" void kernel_launch(void* const* d_in, const int* in_sizes, int n_in,
                              void* d_out, int out_size, void* d_ws, size_t ws_size,
                              hipStream_t stream)
{
  (void)in_sizes; (void)n_in; (void)out_size; (void)ws_size;
  const float* x    = (const float*)d_in[0];
  const float* ew   = (const float*)d_in[1];
  const int*   eidx = (const int*)d_in[2];
  const float* oc_w1 = (const float*)d_in[3];  const float* oc_b1 = (const float*)d_in[4];
  const float* oc_w2 = (const float*)d_in[5];  const float* oc_b2 = (const float*)d_in[6];
  const float* oc_w3 = (const float*)d_in[7];  const float* oc_b3 = (const float*)d_in[8];
  const float* ip_w1 = (const float*)d_in[9];  const float* ip_b1 = (const float*)d_in[10];
  const float* ip_w2 = (const float*)d_in[11]; const float* ip_b2 = (const float*)d_in[12];
  const float* ip_w3 = (const float*)d_in[13]; const float* ip_b3 = (const float*)d_in[14];
  const float* rc_w1 = (const float*)d_in[15]; const float* rc_b1 = (const float*)d_in[16];
  const float* rc_w2 = (const float*)d_in[17]; const float* rc_b2 = (const float*)d_in[18];
  const float* rc_w3 = (const float*)d_in[19]; const float* rc_b3 = (const float*)d_in[20];
  const float* at_iw = (const float*)d_in[21]; const float* at_ib = (const float*)d_in[22];
  const float* at_ow = (const float*)d_in[23]; const float* at_ob = (const float*)d_in[24];

  float* out = (float*)d_out;
  float* out_oc  = out;            // [2,256,8]
  float* out_rel = out + 4096;     // [2,32640,8]
  float* out_imp = out + 526336;   // [2,256,1]
  float* out_att = out + 526848;   // [2,256,768]
  float* out_aw  = out + 920064;   // [2,256,256]

  char* wp = (char*)d_ws;
  auto alloc = [&](size_t bytes) { char* p = wp; wp += (bytes + 255) & ~(size_t)255; return p; };
  float* logP  = (float*)alloc((size_t)4 * 65280 * 8 * 4);    // 8.4 MB
  float* selfF = (float*)alloc((size_t)512 * 768 * 4);
  bf16* AfB  = (bf16*)alloc((size_t)512 * 768 * 2);
  bf16* BfB  = (bf16*)alloc((size_t)512 * 768 * 2);
  bf16* xb   = (bf16*)alloc((size_t)512 * 768 * 2);
  bf16* g0   = (bf16*)alloc((size_t)512 * 768 * 2);
  bf16* g1   = (bf16*)alloc((size_t)512 * 768 * 2);
  bf16* hA   = (bf16*)alloc((size_t)512 * 768 * 2);
  bf16* hB   = (bf16*)alloc((size_t)512 * 384 * 2);
  bf16* hI1  = (bf16*)alloc((size_t)512 * 384 * 2);
  bf16* hI2  = (bf16*)alloc((size_t)512 * 192 * 2);
  bf16* aggB = (bf16*)alloc((size_t)512 * 768 * 2);
  bf16* qkv  = (bf16*)alloc((size_t)512 * 2304 * 2);
  bf16* ctx  = (bf16*)alloc((size_t)512 * 768 * 2);
  bf16* attB = (bf16*)alloc((size_t)512 * 768 * 2);
  bf16* w_oc1 = (bf16*)alloc((size_t)768 * 768 * 2);
  bf16* w_oc2 = (bf16*)alloc((size_t)384 * 768 * 2);
  bf16* w_ip1 = (bf16*)alloc((size_t)384 * 768 * 2);
  bf16* w_ip2 = (bf16*)alloc((size_t)192 * 384 * 2);
  bf16* w_rc1 = (bf16*)alloc((size_t)768 * 1536 * 2);
  bf16* w_rc2 = (bf16*)alloc((size_t)384 * 768 * 2);
  bf16* w_aiw = (bf16*)alloc((size_t)2304 * 768 * 2);
  bf16* w_aow = (bf16*)alloc((size_t)768 * 768 * 2);
  bf16* w_gnn[6];
  for (int i = 0; i < 6; ++i) w_gnn[i] = (bf16*)alloc((size_t)768 * 768 * 2);
  int2* pairs = (int2*)alloc((size_t)NPAIR * 8);
  int* estart = (int*)alloc(257 * 4);
  int* bucket = (int*)alloc((size_t)EE * 4);

  dim3 blk(256);
  dim3 blk128(128);

  CJobs cj;
  cj.j[0]  = { x,     xb,    512 * 768 };
  cj.j[1]  = { oc_w1, w_oc1, 768 * 768 };
  cj.j[2]  = { oc_w2, w_oc2, 384 * 768 };
  cj.j[3]  = { ip_w1, w_ip1, 384 * 768 };
  cj.j[4]  = { ip_w2, w_ip2, 192 * 384 };
  cj.j[5]  = { rc_w1, w_rc1, 768 * 1536 };
  cj.j[6]  = { rc_w2, w_rc2, 384 * 768 };
  cj.j[7]  = { at_iw, w_aiw, 2304 * 768 };
  cj.j[8]  = { at_ow, w_aow, 768 * 768 };
  for (int l = 0; l < 3; ++l) {
    cj.j[9 + 2 * l]  = { (const float*)d_in[25 + l * 6 + 0], w_gnn[2 * l],     768 * 768 };
    cj.j[10 + 2 * l] = { (const float*)d_in[25 + l * 6 + 2], w_gnn[2 * l + 1], 768 * 768 };
  }
  hipMemsetAsync(out_aw, 0, (size_t)NB * NN * NN * 4, stream);   // attn mean accumulator
  preamble<<<dim3(128, 17), blk, 0, stream>>>(cj, eidx, estart, bucket, pairs);

  // object classifier + importance, layer 1 then layer 2 (merged launches)
  {
    LinJob a = { xb, w_oc1, 768, 0, oc_b1, nullptr, hA,  nullptr, 768, 768, 1, 24 };
    LinJob b = { xb, w_ip1, 768, 0, ip_b1, nullptr, hI1, nullptr, 384, 768, 1, 12 };
    linear_mfma2<<<dim3(16, 24, 2), blk128, 0, stream>>>(a, b);
  }
  {
    LinJob a = { hA,  w_oc2, 768, 0, oc_b2, nullptr, hB,  nullptr, 384, 768, 1, 12 };
    LinJob b = { hI1, w_ip2, 384, 0, ip_b2, nullptr, hI2, nullptr, 192, 384, 1, 6 };
    linear_mfma2<<<dim3(16, 12, 2), blk128, 0, stream>>>(a, b);
  }
  small_heads<<<64, blk, 0, stream>>>(hB, oc_w3, oc_b3, out_oc, hI2, ip_w3, ip_b3, out_imp);

  // GNN x3: fused (self-linear + agg), then fused (neigh-linear + LN)
  const bf16* gcur = xb;
  bf16* gbufs[2] = { g0, g1 };
  for (int l = 0; l < 3; ++l) {
    const float* bs_ = (const float*)d_in[25 + l * 6 + 1];
    const float* bn_ = (const float*)d_in[25 + l * 6 + 3];
    const float* gm_ = (const float*)d_in[25 + l * 6 + 4];
    const float* bt_ = (const float*)d_in[25 + l * 6 + 5];
    gnn_stage1<<<704, blk, 0, stream>>>(gcur, w_gnn[2 * l], bs_, selfF, ew, eidx, estart, bucket, aggB);
    gnn_stage2<<<32, blk, 0, stream>>>(aggB, w_gnn[2 * l + 1], bn_, selfF, gm_, bt_, gbufs[l & 1]);
    gcur = gbufs[l & 1];
  }

  // attention (mean-over-heads fused via atomics into out_aw)
  linear_mfma<<<dim3(16, 72), blk128, 0, stream>>>(gcur, w_aiw, 768, 0, at_ib, nullptr, qkv, nullptr, 2304, 768, 0);
  attn_kernel<<<dim3(256, 8, 2), blk, 0, stream>>>(qkv, out_aw, ctx);
  linear_mfma<<<dim3(16, 24), blk128, 0, stream>>>(ctx, w_aow, 768, 0, at_ob, nullptr, attB, out_att, 768, 768, 0);

  // relation: A = att@W1a^T + b1, Bv = att@W1b^T (one merged launch)
  {
    LinJob a = { attB, w_rc1, 1536, 0,   rc_b1,  nullptr, AfB, nullptr, 768, 768, 0, 24 };
    LinJob b = { attB, w_rc1, 1536, 768, nullptr, nullptr, BfB, nullptr, 768, 768, 0, 24 };
    linear_mfma2<<<dim3(16, 24, 2), blk128, 0, stream>>>(a, b);
  }
  // h2 GEMM with fused head -> logit partials; then tiny softmax
  h2_gemm<<<dim3(510, 2), blk, 0, stream>>>(AfB, BfB, w_rc2, rc_b2, rc_w3, pairs, logP);
  relsoftmax<<<255, blk, 0, stream>>>(logP, rc_b3, out_rel);
}

// Round 12
// 460.257 us; speedup vs baseline: 1.2149x; 1.2149x over previous
//
#include <hip/hip_runtime.h>
#include <hip/hip_bf16.h>

typedef __bf16 bf16;
typedef __bf16 bf16x4 __attribute__((ext_vector_type(4)));
typedef __bf16 bf16x8 __attribute__((ext_vector_type(8)));
typedef float  f32x4  __attribute__((ext_vector_type(4)));

#define NB 2
#define NN 256
#define DD 768
#define EE 8192
#define NPAIR 32640

__device__ inline float wred_sum(float v) {
#pragma unroll
  for (int o = 32; o > 0; o >>= 1) v += __shfl_down(v, o, 64);
  return v;
}

typedef const __attribute__((address_space(1))) void GASV;
typedef __attribute__((address_space(3))) void LASV;
__device__ __forceinline__ void async_cp16(const void* g, void* l) {
  __builtin_amdgcn_global_load_lds((GASV*)g, (LASV*)l, 16, 0, 0);
}

// ---- preamble: f32->bf16 converts + edge buckets + pair table, ONE launch ----
struct CJob { const float* s; bf16* d; int n; };
struct CJobs { CJob j[15]; };
__global__ __launch_bounds__(256) void preamble(
    CJobs jobs, const int* __restrict__ eidx, int* __restrict__ estart,
    int* __restrict__ bucket, int2* __restrict__ pairs)
{
  int by = blockIdx.y, t = threadIdx.x;
  if (by < 15) {
    const CJob jb = jobs.j[by];
    int nv = jb.n >> 2;
    for (int i = blockIdx.x * 256 + t; i < nv; i += gridDim.x * 256) {
      float4 v = ((const float4*)jb.s)[i];
      bf16x4 pk = { (bf16)v.x, (bf16)v.y, (bf16)v.z, (bf16)v.w };
      *(bf16x4*)(jb.d + 4 * i) = pk;
    }
  } else if (by == 15) {
    if (blockIdx.x != 0) return;
    __shared__ int tg[EE];   // 32 KB
    __shared__ int cnt[256];
    __shared__ int sst[257];
    cnt[t] = 0;
    for (int e = t; e < EE; e += 256) tg[e] = eidx[2 * e + 1];
    __syncthreads();
    for (int e = t; e < EE; e += 256) atomicAdd(&cnt[tg[e]], 1);
    __syncthreads();
    if (t == 0) { int s = 0; for (int i = 0; i < 256; ++i) { sst[i] = s; s += cnt[i]; } sst[256] = s; }
    __syncthreads();
    estart[t] = sst[t];
    if (t == 0) estart[256] = sst[256];
    cnt[t] = sst[t];
    __syncthreads();
    for (int e = t; e < EE; e += 256) {
      int p = atomicAdd(&cnt[tg[e]], 1);
      bucket[p] = e;
    }
  } else {
#pragma unroll
    for (int u = 0; u < 2; ++u) {
      int i = blockIdx.x + u * 128;
      if (i < 255) {
        int off = i * 255 - (i * (i - 1)) / 2;
        for (int j = i + 1 + t; j < NN; j += 256)
          pairs[off + (j - i - 1)] = make_int2(i, j);
      }
    }
  }
}

// GEMM core: one wave computes a 16x32 tile at (m0, n0). lane = tid&63.
__device__ __forceinline__ void lin_core(
    int m0, int n0, const bf16* __restrict__ X, const bf16* __restrict__ W,
    int ldw, int wofs, const float* __restrict__ bias, const float* __restrict__ addF,
    bf16* __restrict__ outB, float* __restrict__ outF, int N, int K, int act)
{
  int lane = threadIdx.x & 63, lr = lane & 15, lq = lane >> 4;
  const bf16* xrow = X + (size_t)(m0 + lr) * K;
  const bf16* wbase = W + (size_t)wofs;
  f32x4 acc[2] = {};
  for (int k = 0; k < K; k += 32) {
    bf16x8 a = *(const bf16x8*)(xrow + k + lq * 8);
    bf16x8 b0 = *(const bf16x8*)(wbase + (size_t)(n0 + lr) * ldw + k + lq * 8);
    bf16x8 b1 = *(const bf16x8*)(wbase + (size_t)(n0 + 16 + lr) * ldw + k + lq * 8);
    acc[0] = __builtin_amdgcn_mfma_f32_16x16x32_bf16(a, b0, acc[0], 0, 0, 0);
    acc[1] = __builtin_amdgcn_mfma_f32_16x16x32_bf16(a, b1, acc[1], 0, 0, 0);
  }
#pragma unroll
  for (int t = 0; t < 2; ++t) {
    int col = n0 + t * 16 + lr;
    float bv = bias ? bias[col] : 0.0f;
#pragma unroll
    for (int r = 0; r < 4; ++r) {
      int row = m0 + lq * 4 + r;
      size_t o = (size_t)row * N + col;
      float v = acc[t][r] + bv;
      if (addF) v += addF[o];
      if (act) v = fmaxf(v, 0.0f);
      if (outB) outB[o] = (bf16)v;
      if (outF) outF[o] = v;
    }
  }
}

__global__ __launch_bounds__(128) void linear_mfma(
    const bf16* __restrict__ X, const bf16* __restrict__ W, int ldw, int wofs,
    const float* __restrict__ bias, const float* __restrict__ addF,
    bf16* __restrict__ outB, float* __restrict__ outF,
    int N, int K, int act)
{
  int wave = threadIdx.x >> 6;
  lin_core((blockIdx.x * 2 + wave) * 16, blockIdx.y * 32,
           X, W, ldw, wofs, bias, addF, outB, outF, N, K, act);
}

// Two independent GEMMs in one launch; blockIdx.z picks the job.
struct LinJob {
  const bf16* X; const bf16* W; int ldw; int wofs;
  const float* bias; const float* addF; bf16* outB; float* outF;
  int N, K, act, gy;
};
__global__ __launch_bounds__(128) void linear_mfma2(LinJob j0, LinJob j1)
{
  LinJob j = blockIdx.z ? j1 : j0;
  if ((int)blockIdx.y >= j.gy) return;
  int wave = threadIdx.x >> 6;
  lin_core((blockIdx.x * 2 + wave) * 16, blockIdx.y * 32,
           j.X, j.W, j.ldw, j.wofs, j.bias, j.addF, j.outB, j.outF, j.N, j.K, j.act);
}

// GNN stage-1: self-linear (blocks 0..191) + edge aggregation (blocks 192..703)
__global__ __launch_bounds__(256) void gnn_stage1(
    const bf16* __restrict__ g, const bf16* __restrict__ ws, const float* __restrict__ bs,
    float* __restrict__ selfF,
    const float* __restrict__ ew, const int* __restrict__ eidx,
    const int* __restrict__ estart, const int* __restrict__ bucket, bf16* __restrict__ agg)
{
  int bid = blockIdx.x, t = threadIdx.x;
  if (bid < 192) {
    int wave = t >> 6;
    lin_core(((bid & 7) * 4 + wave) * 16, (bid >> 3) * 32,
             g, ws, 768, 0, bs, nullptr, nullptr, selfF, 768, 768, 0);
    return;
  }
  __shared__ int   ssrc[256];
  __shared__ float sw[256];
  int e0 = bid - 192;
  int tgt = e0 & 255, b = e0 >> 8;
  int s = estart[tgt], e = estart[tgt + 1];
  s = max(0, min(s, EE));
  e = max(s, min(e, EE));
  const bf16* gb = g + (size_t)b * NN * DD;
  float a0 = 0, a1 = 0, a2 = 0, a3 = 0;
  for (int base = s; base < e; base += 256) {
    int nchunk = min(256, e - base);
    if (t < nchunk) {
      int eid = bucket[base + t];
      eid = max(0, min(eid, EE - 1));
      ssrc[t] = eidx[2 * eid] & (NN - 1);
      sw[t] = ew[eid];
    }
    __syncthreads();
    if (t < 192) {
      for (int q = 0; q < nchunk; ++q) {
        float w = sw[q];
        bf16x4 v = *(const bf16x4*)(gb + (size_t)ssrc[q] * DD + 4 * t);
        a0 += w * (float)v[0]; a1 += w * (float)v[1];
        a2 += w * (float)v[2]; a3 += w * (float)v[3];
      }
    }
    __syncthreads();
  }
  if (t < 192) {
    bf16x4 o = { (bf16)a0, (bf16)a1, (bf16)a2, (bf16)a3 };
    *(bf16x4*)(agg + ((size_t)b * NN + tgt) * DD + 4 * t) = o;
  }
}

// LayerNorm over f32 rows -> bf16 out. (R9 structure: 512 blocks — the 32-block
// fused stage2 was a 3x-slower latency trap; measured +60us wall in R11.)
__global__ __launch_bounds__(256) void layer_norm(
    const float* __restrict__ o, const float* __restrict__ gm,
    const float* __restrict__ bt, bf16* __restrict__ gout)
{
  __shared__ float red[8];
  int row = blockIdx.x, t = threadIdx.x;
  const float* orow = o + (size_t)row * DD;
  float v0 = orow[t], v1 = orow[t + 256], v2 = orow[t + 512];
  float s = v0 + v1 + v2;
  float q = v0 * v0 + v1 * v1 + v2 * v2;
  float ws_ = wred_sum(s), wq = wred_sum(q);
  if ((t & 63) == 0) { red[t >> 6] = ws_; red[4 + (t >> 6)] = wq; }
  __syncthreads();
  float S = red[0] + red[1] + red[2] + red[3];
  float Q = red[4] + red[5] + red[6] + red[7];
  float mu = S * (1.0f / 768.0f);
  float var = Q * (1.0f / 768.0f) - mu * mu;
  float rstd = rsqrtf(var + 1e-5f);
  bf16* gr = gout + (size_t)row * DD;
  gr[t]       = (bf16)(gm[t]       * (v0 - mu) * rstd + bt[t]);
  gr[t + 256] = (bf16)(gm[t + 256] * (v1 - mu) * rstd + bt[t + 256]);
  gr[t + 512] = (bf16)(gm[t + 512] * (v2 - mu) * rstd + bt[t + 512]);
}

// grid (q=256, h=8, b=2); one block per (b,h,q) row.
__global__ __launch_bounds__(256) void attn_kernel(
    const bf16* __restrict__ qkv, float* __restrict__ aw, bf16* __restrict__ ctx)
{
  __shared__ float qs[96];
  __shared__ float ps[256];
  __shared__ float part[192];
  __shared__ float red[8];
  int qi = blockIdx.x, h = blockIdx.y, b = blockIdx.z, t = threadIdx.x;
  const bf16* qrow = qkv + ((size_t)(b * NN + qi)) * 2304 + h * 96;
  if (t < 96) qs[t] = (float)qrow[t];
  __syncthreads();
  const bf16* krow = qkv + ((size_t)(b * NN + t)) * 2304 + 768 + h * 96;
  float s = 0;
#pragma unroll
  for (int i = 0; i < 12; ++i) {
    bf16x8 kv = *(const bf16x8*)(krow + 8 * i);
#pragma unroll
    for (int j = 0; j < 8; ++j) s += qs[8 * i + j] * (float)kv[j];
  }
  s *= 0.10206207261596577f; // 1/sqrt(96)
  float wm = s;
#pragma unroll
  for (int o = 32; o > 0; o >>= 1) wm = fmaxf(wm, __shfl_down(wm, o, 64));
  if ((t & 63) == 0) red[t >> 6] = wm;
  __syncthreads();
  float MX = fmaxf(fmaxf(red[0], red[1]), fmaxf(red[2], red[3]));
  float e = expf(s - MX);
  float wsum = wred_sum(e);
  if ((t & 63) == 0) red[4 + (t >> 6)] = wsum;
  __syncthreads();
  float SUM = red[4] + red[5] + red[6] + red[7];
  float p = e / SUM;
  ps[t] = p;
  atomicAdd(&aw[((size_t)(b * NN + qi)) * NN + t], p * 0.125f);
  __syncthreads();
  if (t < 192) {
    int d = t % 96, half = t / 96;
    const bf16* vbase = qkv + (size_t)b * NN * 2304 + 1536 + h * 96 + d;
    float a0 = 0, a1 = 0, a2 = 0, a3 = 0;
    int k0 = half * 128;
    for (int k = k0; k < k0 + 128; k += 4) {
      a0 += ps[k]     * (float)vbase[(size_t)k * 2304];
      a1 += ps[k + 1] * (float)vbase[(size_t)(k + 1) * 2304];
      a2 += ps[k + 2] * (float)vbase[(size_t)(k + 2) * 2304];
      a3 += ps[k + 3] * (float)vbase[(size_t)(k + 3) * 2304];
    }
    part[t] = (a0 + a1) + (a2 + a3);
  }
  __syncthreads();
  if (t < 96)
    ctx[((size_t)(b * NN + qi)) * DD + h * 96 + t] = (bf16)(part[t] + part[t + 96]);
}

// oc softmax head (blocks 0..31) + ip sigmoid head (blocks 32..63), one launch.
__global__ __launch_bounds__(256) void small_heads(
    const bf16* __restrict__ hOC, const float* __restrict__ w3, const float* __restrict__ b3,
    float* __restrict__ outOC,
    const bf16* __restrict__ hIP, const float* __restrict__ w1, const float* __restrict__ b1,
    float* __restrict__ outIP)
{
  int t = threadIdx.x;
  int wave = t >> 6, lane = t & 63;
  if (blockIdx.x < 32) {
    __shared__ float sw3[8 * 384];
    for (int i = t; i < 8 * 384; i += 256) sw3[i] = w3[i];
    __syncthreads();
    int k0 = lane * 6;
#pragma unroll
    for (int i = 0; i < 4; ++i) {
      int r = blockIdx.x * 16 + wave * 4 + i;
      const bf16* hr = hOC + (size_t)r * 384;
      float hv[6];
#pragma unroll
      for (int j = 0; j < 6; ++j) hv[j] = (float)hr[k0 + j];
      float lg[8];
#pragma unroll
      for (int c = 0; c < 8; ++c) {
        float p = 0;
#pragma unroll
        for (int j = 0; j < 6; ++j) p += hv[j] * sw3[c * 384 + k0 + j];
        lg[c] = wred_sum(p);
      }
      if (lane == 0) {
        float mx = lg[0] + b3[0];
#pragma unroll
        for (int c = 0; c < 8; ++c) { lg[c] += b3[c]; mx = fmaxf(mx, lg[c]); }
        float ex[8], sum = 0;
#pragma unroll
        for (int c = 0; c < 8; ++c) { ex[c] = expf(lg[c] - mx); sum += ex[c]; }
        float inv = 1.0f / sum;
#pragma unroll
        for (int c = 0; c < 8; ++c) outOC[(size_t)r * 8 + c] = ex[c] * inv;
      }
    }
  } else {
    __shared__ float sw1[192];
    if (t < 192) sw1[t] = w1[t];
    __syncthreads();
    int k0 = lane * 3;
#pragma unroll
    for (int i = 0; i < 4; ++i) {
      int r = (blockIdx.x - 32) * 16 + wave * 4 + i;
      const bf16* hr = hIP + (size_t)r * 192;
      float p = (float)hr[k0] * sw1[k0] + (float)hr[k0 + 1] * sw1[k0 + 1]
              + (float)hr[k0 + 2] * sw1[k0 + 2];
      float s = wred_sum(p);
      if (lane == 0) outIP[r] = 1.0f / (1.0f + expf(-(s + b1[0])));
    }
  }
}

// Relation hidden GEMM + FUSED head partials (verified correct R10/R11).
__global__ __launch_bounds__(256) void h2_gemm(
    const bf16* __restrict__ Af, const bf16* __restrict__ Bf,
    const bf16* __restrict__ w2, const float* __restrict__ b2,
    const float* __restrict__ w3, const int2* __restrict__ pairs,
    float* __restrict__ logP)
{
  __shared__ bf16x8 sh1[512];   // 8 KB  (128 rows x 4 planes)
  __shared__ bf16x8 sw2[768];   // 12 KB (192 rows x 4 planes)
  __shared__ int rA[128], rB[128];
  int tid = threadIdx.x;
  int r0 = blockIdx.x * 128;
  int bb = (r0 >= NPAIR) ? 1 : 0;   // tiles never straddle batches (32640%128==0)
  int n0 = blockIdx.y * 192;
  if (tid < 128) {
    int2 ij = pairs[r0 - bb * NPAIR + tid];
    rA[tid] = (bb * NN + ij.x) * DD;
    rB[tid] = (bb * NN + ij.y) * DD;
  }
  __syncthreads();
  int hrow = tid >> 1, hp = (tid & 1) * 2;
  const bf16* ar = Af + rA[hrow] + hp * 8;
  const bf16* br = Bf + rB[hrow] + hp * 8;
  int hslot = ((hrow >> 4) << 6) + (hp << 4) + (hrow & 15);
  int srow[3], spl[3];
#pragma unroll
  for (int q = 0; q < 3; ++q) {
    int a = q * 256 + tid;
    srow[q] = ((a >> 6) << 4) + (a & 15);
    spl[q] = (a >> 4) & 3;
  }
  int wave = tid >> 6, lane = tid & 63, lr = lane & 15, lq = lane >> 4;
  int wr = wave >> 1, wc = wave & 1;
  f32x4 acc[4][6] = {};
  for (int k0 = 0; k0 < 768; k0 += 32) {
#pragma unroll
    for (int q = 0; q < 3; ++q)
      async_cp16(w2 + (size_t)(n0 + srow[q]) * 768 + k0 + spl[q] * 8,
                 (char*)sw2 + (q * 256 + tid) * 16);
    bf16x8 a0 = *(const bf16x8*)(ar + k0);
    bf16x8 a1 = *(const bf16x8*)(ar + k0 + 8);
    bf16x8 b0 = *(const bf16x8*)(br + k0);
    bf16x8 b1 = *(const bf16x8*)(br + k0 + 8);
    bf16x8 h0, h1v;
#pragma unroll
    for (int j = 0; j < 8; ++j) {
      h0[j]  = (bf16)fmaxf((float)a0[j] + (float)b0[j], 0.f);
      h1v[j] = (bf16)fmaxf((float)a1[j] + (float)b1[j], 0.f);
    }
    sh1[hslot] = h0;
    sh1[hslot + 16] = h1v;
    __syncthreads();
    bf16x8 af[4], bfr[6];
#pragma unroll
    for (int rf = 0; rf < 4; ++rf)
      af[rf] = sh1[(wr * 4 + rf) * 64 + lq * 16 + lr];
#pragma unroll
    for (int cf = 0; cf < 6; ++cf)
      bfr[cf] = sw2[(wc * 6 + cf) * 64 + lq * 16 + lr];
#pragma unroll
    for (int rf = 0; rf < 4; ++rf)
#pragma unroll
      for (int cf = 0; cf < 6; ++cf)
        acc[rf][cf] = __builtin_amdgcn_mfma_f32_16x16x32_bf16(af[rf], bfr[cf], acc[rf][cf], 0, 0, 0);
    __syncthreads();   // also frees sh1/sw2 for epilogue reuse on last iter
  }
  // ---- fused relation head ----
  char* zone = (wave < 2) ? ((char*)sw2 + wave * 3328)
                          : ((char*)sh1 + (wave - 2) * 3328);
  bf16x8 w3f[3];
#pragma unroll
  for (int ks = 0; ks < 3; ++ks) {
    bf16x8 f = {};
    if (lr < 8) {
      const float* wsrc = w3 + lr * 384 + n0 + wc * 96 + ks * 32 + lq * 8;
#pragma unroll
      for (int j = 0; j < 8; ++j) f[j] = (bf16)wsrc[j];
    }
    w3f[ks] = f;
  }
  float* lp = logP + (size_t)((n0 >= 192 ? 2 : 0) + wc) * 65280 * 8;
  bf16* zb = (bf16*)zone;
#pragma unroll
  for (int rf = 0; rf < 4; ++rf) {
#pragma unroll
    for (int cf = 0; cf < 6; ++cf) {
      int col = n0 + wc * 96 + cf * 16 + lr;
      float bv2 = b2[col];
#pragma unroll
      for (int r = 0; r < 4; ++r)
        zb[(lq * 4 + r) * 104 + cf * 16 + lr] = (bf16)fmaxf(acc[rf][cf][r] + bv2, 0.f);
    }
    f32x4 lacc = {};
#pragma unroll
    for (int ks = 0; ks < 3; ++ks) {
      bf16x8 afr = *(const bf16x8*)(zone + lr * 208 + ks * 64 + lq * 16);
      lacc = __builtin_amdgcn_mfma_f32_16x16x32_bf16(afr, w3f[ks], lacc, 0, 0, 0);
    }
    if (lr < 8) {
#pragma unroll
      for (int r = 0; r < 4; ++r) {
        int grow = r0 + wr * 64 + rf * 16 + lq * 4 + r;
        lp[(size_t)grow * 8 + lr] = lacc[r];
      }
    }
  }
}

// Sum 4 logit partials + bias, softmax, write out_rel. Thread = one pair-row.
__global__ __launch_bounds__(256) void relsoftmax(
    const float* __restrict__ logP, const float* __restrict__ b3,
    float* __restrict__ out)
{
  int row = blockIdx.x * 256 + threadIdx.x;   // grid 255*256 = 65280
  float lg[8];
#pragma unroll
  for (int c = 0; c < 8; ++c) lg[c] = b3[c];
#pragma unroll
  for (int p = 0; p < 4; ++p) {
    const float* lp = logP + ((size_t)p * 65280 + row) * 8;
#pragma unroll
    for (int c = 0; c < 8; ++c) lg[c] += lp[c];
  }
  float mx = lg[0];
#pragma unroll
  for (int c = 1; c < 8; ++c) mx = fmaxf(mx, lg[c]);
  float ex[8], sum = 0;
#pragma unroll
  for (int c = 0; c < 8; ++c) { ex[c] = expf(lg[c] - mx); sum += ex[c]; }
  float inv = 1.0f / sum;
#pragma unroll
  for (int c = 0; c < 8; ++c) out[(size_t)row * 8 + c] = ex[c] * inv;
}

extern "C" void kernel_launch(void* const* d_in, const int* in_sizes, int n_in,
                              void* d_out, int out_size, void* d_ws, size_t ws_size,
                              hipStream_t stream)
{
  (void)in_sizes; (void)n_in; (void)out_size; (void)ws_size;
  const float* x    = (const float*)d_in[0];
  const float* ew   = (const float*)d_in[1];
  const int*   eidx = (const int*)d_in[2];
  const float* oc_w1 = (const float*)d_in[3];  const float* oc_b1 = (const float*)d_in[4];
  const float* oc_w2 = (const float*)d_in[5];  const float* oc_b2 = (const float*)d_in[6];
  const float* oc_w3 = (const float*)d_in[7];  const float* oc_b3 = (const float*)d_in[8];
  const float* ip_w1 = (const float*)d_in[9];  const float* ip_b1 = (const float*)d_in[10];
  const float* ip_w2 = (const float*)d_in[11]; const float* ip_b2 = (const float*)d_in[12];
  const float* ip_w3 = (const float*)d_in[13]; const float* ip_b3 = (const float*)d_in[14];
  const float* rc_w1 = (const float*)d_in[15]; const float* rc_b1 = (const float*)d_in[16];
  const float* rc_w2 = (const float*)d_in[17]; const float* rc_b2 = (const float*)d_in[18];
  const float* rc_w3 = (const float*)d_in[19]; const float* rc_b3 = (const float*)d_in[20];
  const float* at_iw = (const float*)d_in[21]; const float* at_ib = (const float*)d_in[22];
  const float* at_ow = (const float*)d_in[23]; const float* at_ob = (const float*)d_in[24];

  float* out = (float*)d_out;
  float* out_oc  = out;            // [2,256,8]
  float* out_rel = out + 4096;     // [2,32640,8]
  float* out_imp = out + 526336;   // [2,256,1]
  float* out_att = out + 526848;   // [2,256,768]
  float* out_aw  = out + 920064;   // [2,256,256]

  char* wp = (char*)d_ws;
  auto alloc = [&](size_t bytes) { char* p = wp; wp += (bytes + 255) & ~(size_t)255; return p; };
  float* logP  = (float*)alloc((size_t)4 * 65280 * 8 * 4);    // 8.4 MB
  float* selfF = (float*)alloc((size_t)512 * 768 * 4);
  float* oBuf  = (float*)alloc((size_t)512 * 768 * 4);
  bf16* AfB  = (bf16*)alloc((size_t)512 * 768 * 2);
  bf16* BfB  = (bf16*)alloc((size_t)512 * 768 * 2);
  bf16* xb   = (bf16*)alloc((size_t)512 * 768 * 2);
  bf16* g0   = (bf16*)alloc((size_t)512 * 768 * 2);
  bf16* g1   = (bf16*)alloc((size_t)512 * 768 * 2);
  bf16* hA   = (bf16*)alloc((size_t)512 * 768 * 2);
  bf16* hB   = (bf16*)alloc((size_t)512 * 384 * 2);
  bf16* hI1  = (bf16*)alloc((size_t)512 * 384 * 2);
  bf16* hI2  = (bf16*)alloc((size_t)512 * 192 * 2);
  bf16* aggB = (bf16*)alloc((size_t)512 * 768 * 2);
  bf16* qkv  = (bf16*)alloc((size_t)512 * 2304 * 2);
  bf16* ctx  = (bf16*)alloc((size_t)512 * 768 * 2);
  bf16* attB = (bf16*)alloc((size_t)512 * 768 * 2);
  bf16* w_oc1 = (bf16*)alloc((size_t)768 * 768 * 2);
  bf16* w_oc2 = (bf16*)alloc((size_t)384 * 768 * 2);
  bf16* w_ip1 = (bf16*)alloc((size_t)384 * 768 * 2);
  bf16* w_ip2 = (bf16*)alloc((size_t)192 * 384 * 2);
  bf16* w_rc1 = (bf16*)alloc((size_t)768 * 1536 * 2);
  bf16* w_rc2 = (bf16*)alloc((size_t)384 * 768 * 2);
  bf16* w_aiw = (bf16*)alloc((size_t)2304 * 768 * 2);
  bf16* w_aow = (bf16*)alloc((size_t)768 * 768 * 2);
  bf16* w_gnn[6];
  for (int i = 0; i < 6; ++i) w_gnn[i] = (bf16*)alloc((size_t)768 * 768 * 2);
  int2* pairs = (int2*)alloc((size_t)NPAIR * 8);
  int* estart = (int*)alloc(257 * 4);
  int* bucket = (int*)alloc((size_t)EE * 4);

  dim3 blk(256);
  dim3 blk128(128);

  CJobs cj;
  cj.j[0]  = { x,     xb,    512 * 768 };
  cj.j[1]  = { oc_w1, w_oc1, 768 * 768 };
  cj.j[2]  = { oc_w2, w_oc2, 384 * 768 };
  cj.j[3]  = { ip_w1, w_ip1, 384 * 768 };
  cj.j[4]  = { ip_w2, w_ip2, 192 * 384 };
  cj.j[5]  = { rc_w1, w_rc1, 768 * 1536 };
  cj.j[6]  = { rc_w2, w_rc2, 384 * 768 };
  cj.j[7]  = { at_iw, w_aiw, 2304 * 768 };
  cj.j[8]  = { at_ow, w_aow, 768 * 768 };
  for (int l = 0; l < 3; ++l) {
    cj.j[9 + 2 * l]  = { (const float*)d_in[25 + l * 6 + 0], w_gnn[2 * l],     768 * 768 };
    cj.j[10 + 2 * l] = { (const float*)d_in[25 + l * 6 + 2], w_gnn[2 * l + 1], 768 * 768 };
  }
  hipMemsetAsync(out_aw, 0, (size_t)NB * NN * NN * 4, stream);   // attn mean accumulator
  preamble<<<dim3(128, 17), blk, 0, stream>>>(cj, eidx, estart, bucket, pairs);

  // object classifier + importance, layer 1 then layer 2 (merged launches)
  {
    LinJob a = { xb, w_oc1, 768, 0, oc_b1, nullptr, hA,  nullptr, 768, 768, 1, 24 };
    LinJob b = { xb, w_ip1, 768, 0, ip_b1, nullptr, hI1, nullptr, 384, 768, 1, 12 };
    linear_mfma2<<<dim3(16, 24, 2), blk128, 0, stream>>>(a, b);
  }
  {
    LinJob a = { hA,  w_oc2, 768, 0, oc_b2, nullptr, hB,  nullptr, 384, 768, 1, 12 };
    LinJob b = { hI1, w_ip2, 384, 0, ip_b2, nullptr, hI2, nullptr, 192, 384, 1, 6 };
    linear_mfma2<<<dim3(16, 12, 2), blk128, 0, stream>>>(a, b);
  }
  small_heads<<<64, blk, 0, stream>>>(hB, oc_w3, oc_b3, out_oc, hI2, ip_w3, ip_b3, out_imp);

  // GNN x3: fused (self-linear + agg), then neigh-linear(+add,relu), then LN
  const bf16* gcur = xb;
  bf16* gbufs[2] = { g0, g1 };
  for (int l = 0; l < 3; ++l) {
    const float* bs_ = (const float*)d_in[25 + l * 6 + 1];
    const float* bn_ = (const float*)d_in[25 + l * 6 + 3];
    const float* gm_ = (const float*)d_in[25 + l * 6 + 4];
    const float* bt_ = (const float*)d_in[25 + l * 6 + 5];
    gnn_stage1<<<704, blk, 0, stream>>>(gcur, w_gnn[2 * l], bs_, selfF, ew, eidx, estart, bucket, aggB);
    linear_mfma<<<dim3(16, 24), blk128, 0, stream>>>(aggB, w_gnn[2 * l + 1], 768, 0, bn_, selfF, nullptr, oBuf, 768, 768, 1);
    layer_norm<<<512, blk, 0, stream>>>(oBuf, gm_, bt_, gbufs[l & 1]);
    gcur = gbufs[l & 1];
  }

  // attention (mean-over-heads fused via atomics into out_aw)
  linear_mfma<<<dim3(16, 72), blk128, 0, stream>>>(gcur, w_aiw, 768, 0, at_ib, nullptr, qkv, nullptr, 2304, 768, 0);
  attn_kernel<<<dim3(256, 8, 2), blk, 0, stream>>>(qkv, out_aw, ctx);
  linear_mfma<<<dim3(16, 24), blk128, 0, stream>>>(ctx, w_aow, 768, 0, at_ob, nullptr, attB, out_att, 768, 768, 0);

  // relation: A = att@W1a^T + b1, Bv = att@W1b^T (one merged launch)
  {
    LinJob a = { attB, w_rc1, 1536, 0,   rc_b1,  nullptr, AfB, nullptr, 768, 768, 0, 24 };
    LinJob b = { attB, w_rc1, 1536, 768, nullptr, nullptr, BfB, nullptr, 768, 768, 0, 24 };
    linear_mfma2<<<dim3(16, 24, 2), blk128, 0, stream>>>(a, b);
  }
  // h2 GEMM with fused head -> logit partials; then tiny softmax
  h2_gemm<<<dim3(510, 2), blk, 0, stream>>>(AfB, BfB, w_rc2, rc_b2, rc_w3, pairs, logP);
  relsoftmax<<<255, blk, 0, stream>>>(logP, rc_b3, out_rel);
}

// Round 13
// 459.671 us; speedup vs baseline: 1.2165x; 1.0013x over previous
//
#include <hip/hip_runtime.h>
#include <hip/hip_bf16.h>

typedef __bf16 bf16;
typedef __bf16 bf16x4 __attribute__((ext_vector_type(4)));
typedef __bf16 bf16x8 __attribute__((ext_vector_type(8)));
typedef float  f32x4  __attribute__((ext_vector_type(4)));
typedef float  f32x8  __attribute__((ext_vector_type(8)));

#define NB 2
#define NN 256
#define DD 768
#define EE 8192
#define NPAIR 32640

__device__ inline float wred_sum(float v) {
#pragma unroll
  for (int o = 32; o > 0; o >>= 1) v += __shfl_down(v, o, 64);
  return v;
}

typedef const __attribute__((address_space(1))) void GASV;
typedef __attribute__((address_space(3))) void LASV;
__device__ __forceinline__ void async_cp16(const void* g, void* l) {
  __builtin_amdgcn_global_load_lds((GASV*)g, (LASV*)l, 16, 0, 0);
}

// ---- preamble: converts + buckets + pairs + out_aw zero, ONE launch ----
struct CJob { const float* s; bf16* d; int n; };
struct CJobs { CJob j[15]; };
__global__ __launch_bounds__(256) void preamble(
    CJobs jobs, const int* __restrict__ eidx, int* __restrict__ estart,
    int* __restrict__ bucket, int2* __restrict__ pairs, float* __restrict__ aw)
{
  int by = blockIdx.y, t = threadIdx.x;
  if (by < 15) {
    const CJob jb = jobs.j[by];
    int nv = jb.n >> 2;
    for (int i = blockIdx.x * 256 + t; i < nv; i += gridDim.x * 256) {
      float4 v = ((const float4*)jb.s)[i];
      bf16x4 pk = { (bf16)v.x, (bf16)v.y, (bf16)v.z, (bf16)v.w };
      *(bf16x4*)(jb.d + 4 * i) = pk;
    }
  } else if (by == 15) {
    if (blockIdx.x != 0) return;
    __shared__ int tg[EE];   // 32 KB
    __shared__ int cnt[256];
    __shared__ int sst[257];
    cnt[t] = 0;
    for (int e = t; e < EE; e += 256) tg[e] = eidx[2 * e + 1];
    __syncthreads();
    for (int e = t; e < EE; e += 256) atomicAdd(&cnt[tg[e]], 1);
    __syncthreads();
    if (t == 0) { int s = 0; for (int i = 0; i < 256; ++i) { sst[i] = s; s += cnt[i]; } sst[256] = s; }
    __syncthreads();
    estart[t] = sst[t];
    if (t == 0) estart[256] = sst[256];
    cnt[t] = sst[t];
    __syncthreads();
    for (int e = t; e < EE; e += 256) {
      int p = atomicAdd(&cnt[tg[e]], 1);
      bucket[p] = e;
    }
  } else if (by == 16) {
#pragma unroll
    for (int u = 0; u < 2; ++u) {
      int i = blockIdx.x + u * 128;
      if (i < 255) {
        int off = i * 255 - (i * (i - 1)) / 2;
        for (int j = i + 1 + t; j < NN; j += 256)
          pairs[off + (j - i - 1)] = make_int2(i, j);
      }
    }
  } else {
    // zero out_aw: 2*256*256 f32 = 32768 float4
    int idx = blockIdx.x * 256 + t;
    ((float4*)aw)[idx] = make_float4(0.f, 0.f, 0.f, 0.f);
  }
}

// GEMM core: one wave computes a 16x32 tile at (m0, n0). lane = tid&63.
__device__ __forceinline__ void lin_core(
    int m0, int n0, const bf16* __restrict__ X, const bf16* __restrict__ W,
    int ldw, int wofs, const float* __restrict__ bias, const float* __restrict__ addF,
    bf16* __restrict__ outB, float* __restrict__ outF, int N, int K, int act)
{
  int lane = threadIdx.x & 63, lr = lane & 15, lq = lane >> 4;
  const bf16* xrow = X + (size_t)(m0 + lr) * K;
  const bf16* wbase = W + (size_t)wofs;
  f32x4 acc[2] = {};
  for (int k = 0; k < K; k += 32) {
    bf16x8 a = *(const bf16x8*)(xrow + k + lq * 8);
    bf16x8 b0 = *(const bf16x8*)(wbase + (size_t)(n0 + lr) * ldw + k + lq * 8);
    bf16x8 b1 = *(const bf16x8*)(wbase + (size_t)(n0 + 16 + lr) * ldw + k + lq * 8);
    acc[0] = __builtin_amdgcn_mfma_f32_16x16x32_bf16(a, b0, acc[0], 0, 0, 0);
    acc[1] = __builtin_amdgcn_mfma_f32_16x16x32_bf16(a, b1, acc[1], 0, 0, 0);
  }
#pragma unroll
  for (int t = 0; t < 2; ++t) {
    int col = n0 + t * 16 + lr;
    float bv = bias ? bias[col] : 0.0f;
#pragma unroll
    for (int r = 0; r < 4; ++r) {
      int row = m0 + lq * 4 + r;
      size_t o = (size_t)row * N + col;
      float v = acc[t][r] + bv;
      if (addF) v += addF[o];
      if (act) v = fmaxf(v, 0.0f);
      if (outB) outB[o] = (bf16)v;
      if (outF) outF[o] = v;
    }
  }
}

// 256-thread (4-wave) M=512 linear section: bid in [0, N/32*8)
__device__ __forceinline__ void lin256(
    int bid, const bf16* X, const bf16* W, int ldw, int wofs,
    const float* bias, const float* addF, bf16* outB, float* outF,
    int N, int K, int act)
{
  int wave = threadIdx.x >> 6;
  lin_core(((bid & 7) * 4 + wave) * 16, (bid >> 3) * 32,
           X, W, ldw, wofs, bias, addF, outB, outF, N, K, act);
}

__global__ __launch_bounds__(128) void linear_mfma(
    const bf16* __restrict__ X, const bf16* __restrict__ W, int ldw, int wofs,
    const float* __restrict__ bias, const float* __restrict__ addF,
    bf16* __restrict__ outB, float* __restrict__ outF,
    int N, int K, int act)
{
  int wave = threadIdx.x >> 6;
  lin_core((blockIdx.x * 2 + wave) * 16, blockIdx.y * 32,
           X, W, ldw, wofs, bias, addF, outB, outF, N, K, act);
}

// Two independent GEMMs in one launch; blockIdx.z picks the job.
struct LinJob {
  const bf16* X; const bf16* W; int ldw; int wofs;
  const float* bias; const float* addF; bf16* outB; float* outF;
  int N, K, act, gy;
};
__global__ __launch_bounds__(128) void linear_mfma2(LinJob j0, LinJob j1)
{
  LinJob j = blockIdx.z ? j1 : j0;
  if ((int)blockIdx.y >= j.gy) return;
  int wave = threadIdx.x >> 6;
  lin_core((blockIdx.x * 2 + wave) * 16, blockIdx.y * 32,
           j.X, j.W, j.ldw, j.wofs, j.bias, j.addF, j.outB, j.outF, j.N, j.K, j.act);
}

// GNN stage-1 body: self-linear (bid 0..191) + edge aggregation (bid 192..703)
__device__ __forceinline__ void gnn_s1_body(
    int bid, const bf16* __restrict__ g, const bf16* __restrict__ ws,
    const float* __restrict__ bs, float* __restrict__ selfF,
    const float* __restrict__ ew, const int* __restrict__ eidx,
    const int* __restrict__ estart, const int* __restrict__ bucket,
    bf16* __restrict__ agg, int* ssrc, float* sw)
{
  int t = threadIdx.x;
  if (bid < 192) {
    lin256(bid, g, ws, 768, 0, bs, nullptr, nullptr, selfF, 768, 768, 0);
    return;
  }
  int e0 = bid - 192;
  int tgt = e0 & 255, b = e0 >> 8;
  int s = estart[tgt], e = estart[tgt + 1];
  s = max(0, min(s, EE));
  e = max(s, min(e, EE));
  const bf16* gb = g + (size_t)b * NN * DD;
  float a0 = 0, a1 = 0, a2 = 0, a3 = 0;
  for (int base = s; base < e; base += 256) {
    int nchunk = min(256, e - base);
    if (t < nchunk) {
      int eid = bucket[base + t];
      eid = max(0, min(eid, EE - 1));
      ssrc[t] = eidx[2 * eid] & (NN - 1);
      sw[t] = ew[eid];
    }
    __syncthreads();
    if (t < 192) {
      for (int q = 0; q < nchunk; ++q) {
        float w = sw[q];
        bf16x4 v = *(const bf16x4*)(gb + (size_t)ssrc[q] * DD + 4 * t);
        a0 += w * (float)v[0]; a1 += w * (float)v[1];
        a2 += w * (float)v[2]; a3 += w * (float)v[3];
      }
    }
    __syncthreads();
  }
  if (t < 192) {
    bf16x4 o = { (bf16)a0, (bf16)a1, (bf16)a2, (bf16)a3 };
    *(bf16x4*)(agg + ((size_t)b * NN + tgt) * DD + 4 * t) = o;
  }
}

__global__ __launch_bounds__(256) void gnn_stage1(
    const bf16* __restrict__ g, const bf16* __restrict__ ws, const float* __restrict__ bs,
    float* __restrict__ selfF,
    const float* __restrict__ ew, const int* __restrict__ eidx,
    const int* __restrict__ estart, const int* __restrict__ bucket, bf16* __restrict__ agg)
{
  __shared__ int   ssrc[256];
  __shared__ float sw[256];
  gnn_s1_body(blockIdx.x, g, ws, bs, selfF, ew, eidx, estart, bucket, agg, ssrc, sw);
}

// MEGA-1: gnn_stage1(l0) [0,704) + oc-L1 [704,896) + ip-L1 [896,992)
__global__ __launch_bounds__(256) void mega1(
    const bf16* __restrict__ xb, const bf16* __restrict__ ws0, const float* __restrict__ bs0,
    float* __restrict__ selfF,
    const float* __restrict__ ew, const int* __restrict__ eidx,
    const int* __restrict__ estart, const int* __restrict__ bucket, bf16* __restrict__ agg,
    const bf16* __restrict__ w_oc1, const float* __restrict__ oc_b1, bf16* __restrict__ hA,
    const bf16* __restrict__ w_ip1, const float* __restrict__ ip_b1, bf16* __restrict__ hI1)
{
  __shared__ int   ssrc[256];
  __shared__ float sw[256];
  int bid = blockIdx.x;
  if (bid < 704)
    gnn_s1_body(bid, xb, ws0, bs0, selfF, ew, eidx, estart, bucket, agg, ssrc, sw);
  else if (bid < 896)
    lin256(bid - 704, xb, w_oc1, 768, 0, oc_b1, nullptr, hA, nullptr, 768, 768, 1);
  else
    lin256(bid - 896, xb, w_ip1, 768, 0, ip_b1, nullptr, hI1, nullptr, 384, 768, 1);
}

// MEGA-2: neigh-linear l0 [0,192) + oc-L2 [192,288) + ip-L2 [288,336)
__global__ __launch_bounds__(256) void mega2(
    const bf16* __restrict__ aggB, const bf16* __restrict__ wn0, const float* __restrict__ bn0,
    const float* __restrict__ selfF, float* __restrict__ oBuf,
    const bf16* __restrict__ hA, const bf16* __restrict__ w_oc2, const float* __restrict__ oc_b2,
    bf16* __restrict__ hB,
    const bf16* __restrict__ hI1, const bf16* __restrict__ w_ip2, const float* __restrict__ ip_b2,
    bf16* __restrict__ hI2)
{
  int bid = blockIdx.x;
  if (bid < 192)
    lin256(bid, aggB, wn0, 768, 0, bn0, selfF, nullptr, oBuf, 768, 768, 1);
  else if (bid < 288)
    lin256(bid - 192, hA, w_oc2, 768, 0, oc_b2, nullptr, hB, nullptr, 384, 768, 1);
  else
    lin256(bid - 288, hI1, w_ip2, 384, 0, ip_b2, nullptr, hI2, nullptr, 192, 384, 1);
}

// LayerNorm body (one row per block-slot)
__device__ __forceinline__ void ln_body(
    int row, const float* __restrict__ o, const float* __restrict__ gm,
    const float* __restrict__ bt, bf16* __restrict__ gout, float* red)
{
  int t = threadIdx.x;
  const float* orow = o + (size_t)row * DD;
  float v0 = orow[t], v1 = orow[t + 256], v2 = orow[t + 512];
  float s = v0 + v1 + v2;
  float q = v0 * v0 + v1 * v1 + v2 * v2;
  float ws_ = wred_sum(s), wq = wred_sum(q);
  if ((t & 63) == 0) { red[t >> 6] = ws_; red[4 + (t >> 6)] = wq; }
  __syncthreads();
  float S = red[0] + red[1] + red[2] + red[3];
  float Q = red[4] + red[5] + red[6] + red[7];
  float mu = S * (1.0f / 768.0f);
  float var = Q * (1.0f / 768.0f) - mu * mu;
  float rstd = rsqrtf(var + 1e-5f);
  bf16* gr = gout + (size_t)row * DD;
  gr[t]       = (bf16)(gm[t]       * (v0 - mu) * rstd + bt[t]);
  gr[t + 256] = (bf16)(gm[t + 256] * (v1 - mu) * rstd + bt[t + 256]);
  gr[t + 512] = (bf16)(gm[t + 512] * (v2 - mu) * rstd + bt[t + 512]);
}

__global__ __launch_bounds__(256) void layer_norm(
    const float* __restrict__ o, const float* __restrict__ gm,
    const float* __restrict__ bt, bf16* __restrict__ gout)
{
  __shared__ float red[8];
  ln_body(blockIdx.x, o, gm, bt, gout, red);
}

// MEGA-3: LN l0 [0,512) + oc softmax head [512,544) + ip sigmoid head [544,576)
__global__ __launch_bounds__(256) void mega3(
    const float* __restrict__ oBuf, const float* __restrict__ gm0,
    const float* __restrict__ bt0, bf16* __restrict__ gout,
    const bf16* __restrict__ hOC, const float* __restrict__ w3, const float* __restrict__ b3,
    float* __restrict__ outOC,
    const bf16* __restrict__ hIP, const float* __restrict__ w1, const float* __restrict__ b1,
    float* __restrict__ outIP)
{
  __shared__ float sh[3072];
  int bid = blockIdx.x, t = threadIdx.x;
  int wave = t >> 6, lane = t & 63;
  if (bid < 512) {
    ln_body(bid, oBuf, gm0, bt0, gout, sh);
  } else if (bid < 544) {
    for (int i = t; i < 8 * 384; i += 256) sh[i] = w3[i];
    __syncthreads();
    int k0 = lane * 6;
#pragma unroll
    for (int i = 0; i < 4; ++i) {
      int r = (bid - 512) * 16 + wave * 4 + i;
      const bf16* hr = hOC + (size_t)r * 384;
      float hv[6];
#pragma unroll
      for (int j = 0; j < 6; ++j) hv[j] = (float)hr[k0 + j];
      float lg[8];
#pragma unroll
      for (int c = 0; c < 8; ++c) {
        float p = 0;
#pragma unroll
        for (int j = 0; j < 6; ++j) p += hv[j] * sh[c * 384 + k0 + j];
        lg[c] = wred_sum(p);
      }
      if (lane == 0) {
        float mx = lg[0] + b3[0];
#pragma unroll
        for (int c = 0; c < 8; ++c) { lg[c] += b3[c]; mx = fmaxf(mx, lg[c]); }
        float ex[8], sum = 0;
#pragma unroll
        for (int c = 0; c < 8; ++c) { ex[c] = expf(lg[c] - mx); sum += ex[c]; }
        float inv = 1.0f / sum;
#pragma unroll
        for (int c = 0; c < 8; ++c) outOC[(size_t)r * 8 + c] = ex[c] * inv;
      }
    }
  } else {
    if (t < 192) sh[t] = w1[t];
    __syncthreads();
    int k0 = lane * 3;
#pragma unroll
    for (int i = 0; i < 4; ++i) {
      int r = (bid - 544) * 16 + wave * 4 + i;
      const bf16* hr = hIP + (size_t)r * 192;
      float p = (float)hr[k0] * sh[k0] + (float)hr[k0 + 1] * sh[k0 + 1]
              + (float)hr[k0 + 2] * sh[k0 + 2];
      float s = wred_sum(p);
      if (lane == 0) outIP[r] = 1.0f / (1.0f + expf(-(s + b1[0])));
    }
  }
}

// grid (q=256, h=8, b=2); one block per (b,h,q) row.
__global__ __launch_bounds__(256) void attn_kernel(
    const bf16* __restrict__ qkv, float* __restrict__ aw, bf16* __restrict__ ctx)
{
  __shared__ float qs[96];
  __shared__ float ps[256];
  __shared__ float part[192];
  __shared__ float red[8];
  int qi = blockIdx.x, h = blockIdx.y, b = blockIdx.z, t = threadIdx.x;
  const bf16* qrow = qkv + ((size_t)(b * NN + qi)) * 2304 + h * 96;
  if (t < 96) qs[t] = (float)qrow[t];
  __syncthreads();
  const bf16* krow = qkv + ((size_t)(b * NN + t)) * 2304 + 768 + h * 96;
  float s = 0;
#pragma unroll
  for (int i = 0; i < 12; ++i) {
    bf16x8 kv = *(const bf16x8*)(krow + 8 * i);
#pragma unroll
    for (int j = 0; j < 8; ++j) s += qs[8 * i + j] * (float)kv[j];
  }
  s *= 0.10206207261596577f; // 1/sqrt(96)
  float wm = s;
#pragma unroll
  for (int o = 32; o > 0; o >>= 1) wm = fmaxf(wm, __shfl_down(wm, o, 64));
  if ((t & 63) == 0) red[t >> 6] = wm;
  __syncthreads();
  float MX = fmaxf(fmaxf(red[0], red[1]), fmaxf(red[2], red[3]));
  float e = expf(s - MX);
  float wsum = wred_sum(e);
  if ((t & 63) == 0) red[4 + (t >> 6)] = wsum;
  __syncthreads();
  float SUM = red[4] + red[5] + red[6] + red[7];
  float p = e / SUM;
  ps[t] = p;
  atomicAdd(&aw[((size_t)(b * NN + qi)) * NN + t], p * 0.125f);
  __syncthreads();
  if (t < 192) {
    int d = t % 96, half = t / 96;
    const bf16* vbase = qkv + (size_t)b * NN * 2304 + 1536 + h * 96 + d;
    float a0 = 0, a1 = 0, a2 = 0, a3 = 0;
    int k0 = half * 128;
    for (int k = k0; k < k0 + 128; k += 4) {
      a0 += ps[k]     * (float)vbase[(size_t)k * 2304];
      a1 += ps[k + 1] * (float)vbase[(size_t)(k + 1) * 2304];
      a2 += ps[k + 2] * (float)vbase[(size_t)(k + 2) * 2304];
      a3 += ps[k + 3] * (float)vbase[(size_t)(k + 3) * 2304];
    }
    part[t] = (a0 + a1) + (a2 + a3);
  }
  __syncthreads();
  if (t < 96)
    ctx[((size_t)(b * NN + qi)) * DD + h * 96 + t] = (bf16)(part[t] + part[t + 96]);
}

// Relation hidden GEMM + FUSED head partials. Af/Bf now f32 (skips the
// bf16 round + unpack in h1-gen; VALU cut, accuracy strictly better).
__global__ __launch_bounds__(256) void h2_gemm(
    const float* __restrict__ Af, const float* __restrict__ Bf,
    const bf16* __restrict__ w2, const float* __restrict__ b2,
    const float* __restrict__ w3, const int2* __restrict__ pairs,
    float* __restrict__ logP)
{
  __shared__ bf16x8 sh1[512];   // 8 KB  (128 rows x 4 planes)
  __shared__ bf16x8 sw2[768];   // 12 KB (192 rows x 4 planes)
  __shared__ int rA[128], rB[128];
  int tid = threadIdx.x;
  int r0 = blockIdx.x * 128;
  int bb = (r0 >= NPAIR) ? 1 : 0;   // tiles never straddle batches (32640%128==0)
  int n0 = blockIdx.y * 192;
  if (tid < 128) {
    int2 ij = pairs[r0 - bb * NPAIR + tid];
    rA[tid] = (bb * NN + ij.x) * DD;
    rB[tid] = (bb * NN + ij.y) * DD;
  }
  __syncthreads();
  int hrow = tid >> 1, hp = (tid & 1) * 2;
  const float* ar = Af + rA[hrow] + hp * 8;
  const float* br = Bf + rB[hrow] + hp * 8;
  int hslot = ((hrow >> 4) << 6) + (hp << 4) + (hrow & 15);
  int srow[3], spl[3];
#pragma unroll
  for (int q = 0; q < 3; ++q) {
    int a = q * 256 + tid;
    srow[q] = ((a >> 6) << 4) + (a & 15);
    spl[q] = (a >> 4) & 3;
  }
  int wave = tid >> 6, lane = tid & 63, lr = lane & 15, lq = lane >> 4;
  int wr = wave >> 1, wc = wave & 1;
  f32x4 acc[4][6] = {};
  for (int k0 = 0; k0 < 768; k0 += 32) {
#pragma unroll
    for (int q = 0; q < 3; ++q)
      async_cp16(w2 + (size_t)(n0 + srow[q]) * 768 + k0 + spl[q] * 8,
                 (char*)sw2 + (q * 256 + tid) * 16);
    f32x8 a0 = *(const f32x8*)(ar + k0);
    f32x8 b0 = *(const f32x8*)(br + k0);
    f32x8 a1 = *(const f32x8*)(ar + k0 + 8);
    f32x8 b1 = *(const f32x8*)(br + k0 + 8);
    bf16x8 h0, h1v;
#pragma unroll
    for (int j = 0; j < 8; ++j) {
      h0[j]  = (bf16)fmaxf(a0[j] + b0[j], 0.f);
      h1v[j] = (bf16)fmaxf(a1[j] + b1[j], 0.f);
    }
    sh1[hslot] = h0;
    sh1[hslot + 16] = h1v;
    __syncthreads();
    bf16x8 af[4], bfr[6];
#pragma unroll
    for (int rf = 0; rf < 4; ++rf)
      af[rf] = sh1[(wr * 4 + rf) * 64 + lq * 16 + lr];
#pragma unroll
    for (int cf = 0; cf < 6; ++cf)
      bfr[cf] = sw2[(wc * 6 + cf) * 64 + lq * 16 + lr];
#pragma unroll
    for (int rf = 0; rf < 4; ++rf)
#pragma unroll
      for (int cf = 0; cf < 6; ++cf)
        acc[rf][cf] = __builtin_amdgcn_mfma_f32_16x16x32_bf16(af[rf], bfr[cf], acc[rf][cf], 0, 0, 0);
    __syncthreads();   // also frees sh1/sw2 for epilogue reuse on last iter
  }
  // ---- fused relation head ----
  char* zone = (wave < 2) ? ((char*)sw2 + wave * 3328)
                          : ((char*)sh1 + (wave - 2) * 3328);
  bf16x8 w3f[3];
#pragma unroll
  for (int ks = 0; ks < 3; ++ks) {
    bf16x8 f = {};
    if (lr < 8) {
      const float* wsrc = w3 + lr * 384 + n0 + wc * 96 + ks * 32 + lq * 8;
#pragma unroll
      for (int j = 0; j < 8; ++j) f[j] = (bf16)wsrc[j];
    }
    w3f[ks] = f;
  }
  float* lp = logP + (size_t)((n0 >= 192 ? 2 : 0) + wc) * 65280 * 8;
  bf16* zb = (bf16*)zone;
#pragma unroll
  for (int rf = 0; rf < 4; ++rf) {
#pragma unroll
    for (int cf = 0; cf < 6; ++cf) {
      int col = n0 + wc * 96 + cf * 16 + lr;
      float bv2 = b2[col];
#pragma unroll
      for (int r = 0; r < 4; ++r)
        zb[(lq * 4 + r) * 104 + cf * 16 + lr] = (bf16)fmaxf(acc[rf][cf][r] + bv2, 0.f);
    }
    f32x4 lacc = {};
#pragma unroll
    for (int ks = 0; ks < 3; ++ks) {
      bf16x8 afr = *(const bf16x8*)(zone + lr * 208 + ks * 64 + lq * 16);
      lacc = __builtin_amdgcn_mfma_f32_16x16x32_bf16(afr, w3f[ks], lacc, 0, 0, 0);
    }
    if (lr < 8) {
#pragma unroll
      for (int r = 0; r < 4; ++r) {
        int grow = r0 + wr * 64 + rf * 16 + lq * 4 + r;
        lp[(size_t)grow * 8 + lr] = lacc[r];
      }
    }
  }
}

// Sum 4 logit partials + bias, softmax, write out_rel. Thread = one pair-row.
__global__ __launch_bounds__(256) void relsoftmax(
    const float* __restrict__ logP, const float* __restrict__ b3,
    float* __restrict__ out)
{
  int row = blockIdx.x * 256 + threadIdx.x;   // grid 255*256 = 65280
  float lg[8];
#pragma unroll
  for (int c = 0; c < 8; ++c) lg[c] = b3[c];
#pragma unroll
  for (int p = 0; p < 4; ++p) {
    const float* lp = logP + ((size_t)p * 65280 + row) * 8;
#pragma unroll
    for (int c = 0; c < 8; ++c) lg[c] += lp[c];
  }
  float mx = lg[0];
#pragma unroll
  for (int c = 1; c < 8; ++c) mx = fmaxf(mx, lg[c]);
  float ex[8], sum = 0;
#pragma unroll
  for (int c = 0; c < 8; ++c) { ex[c] = expf(lg[c] - mx); sum += ex[c]; }
  float inv = 1.0f / sum;
#pragma unroll
  for (int c = 0; c < 8; ++c) out[(size_t)row * 8 + c] = ex[c] * inv;
}

extern "C" void kernel_launch(void* const* d_in, const int* in_sizes, int n_in,
                              void* d_out, int out_size, void* d_ws, size_t ws_size,
                              hipStream_t stream)
{
  (void)in_sizes; (void)n_in; (void)out_size; (void)ws_size;
  const float* x    = (const float*)d_in[0];
  const float* ew   = (const float*)d_in[1];
  const int*   eidx = (const int*)d_in[2];
  const float* oc_w1 = (const float*)d_in[3];  const float* oc_b1 = (const float*)d_in[4];
  const float* oc_w2 = (const float*)d_in[5];  const float* oc_b2 = (const float*)d_in[6];
  const float* oc_w3 = (const float*)d_in[7];  const float* oc_b3 = (const float*)d_in[8];
  const float* ip_w1 = (const float*)d_in[9];  const float* ip_b1 = (const float*)d_in[10];
  const float* ip_w2 = (const float*)d_in[11]; const float* ip_b2 = (const float*)d_in[12];
  const float* ip_w3 = (const float*)d_in[13]; const float* ip_b3 = (const float*)d_in[14];
  const float* rc_w1 = (const float*)d_in[15]; const float* rc_b1 = (const float*)d_in[16];
  const float* rc_w2 = (const float*)d_in[17]; const float* rc_b2 = (const float*)d_in[18];
  const float* rc_w3 = (const float*)d_in[19]; const float* rc_b3 = (const float*)d_in[20];
  const float* at_iw = (const float*)d_in[21]; const float* at_ib = (const float*)d_in[22];
  const float* at_ow = (const float*)d_in[23]; const float* at_ob = (const float*)d_in[24];

  float* out = (float*)d_out;
  float* out_oc  = out;            // [2,256,8]
  float* out_rel = out + 4096;     // [2,32640,8]
  float* out_imp = out + 526336;   // [2,256,1]
  float* out_att = out + 526848;   // [2,256,768]
  float* out_aw  = out + 920064;   // [2,256,256]

  char* wp = (char*)d_ws;
  auto alloc = [&](size_t bytes) { char* p = wp; wp += (bytes + 255) & ~(size_t)255; return p; };
  float* logP  = (float*)alloc((size_t)4 * 65280 * 8 * 4);    // 8.4 MB
  float* selfF = (float*)alloc((size_t)512 * 768 * 4);
  float* oBuf  = (float*)alloc((size_t)512 * 768 * 4);
  float* Af    = (float*)alloc((size_t)512 * 768 * 4);
  float* Bf    = (float*)alloc((size_t)512 * 768 * 4);
  bf16* xb   = (bf16*)alloc((size_t)512 * 768 * 2);
  bf16* g0   = (bf16*)alloc((size_t)512 * 768 * 2);
  bf16* g1   = (bf16*)alloc((size_t)512 * 768 * 2);
  bf16* hA   = (bf16*)alloc((size_t)512 * 768 * 2);
  bf16* hB   = (bf16*)alloc((size_t)512 * 384 * 2);
  bf16* hI1  = (bf16*)alloc((size_t)512 * 384 * 2);
  bf16* hI2  = (bf16*)alloc((size_t)512 * 192 * 2);
  bf16* aggB = (bf16*)alloc((size_t)512 * 768 * 2);
  bf16* qkv  = (bf16*)alloc((size_t)512 * 2304 * 2);
  bf16* ctx  = (bf16*)alloc((size_t)512 * 768 * 2);
  bf16* attB = (bf16*)alloc((size_t)512 * 768 * 2);
  bf16* w_oc1 = (bf16*)alloc((size_t)768 * 768 * 2);
  bf16* w_oc2 = (bf16*)alloc((size_t)384 * 768 * 2);
  bf16* w_ip1 = (bf16*)alloc((size_t)384 * 768 * 2);
  bf16* w_ip2 = (bf16*)alloc((size_t)192 * 384 * 2);
  bf16* w_rc1 = (bf16*)alloc((size_t)768 * 1536 * 2);
  bf16* w_rc2 = (bf16*)alloc((size_t)384 * 768 * 2);
  bf16* w_aiw = (bf16*)alloc((size_t)2304 * 768 * 2);
  bf16* w_aow = (bf16*)alloc((size_t)768 * 768 * 2);
  bf16* w_gnn[6];
  for (int i = 0; i < 6; ++i) w_gnn[i] = (bf16*)alloc((size_t)768 * 768 * 2);
  int2* pairs = (int2*)alloc((size_t)NPAIR * 8);
  int* estart = (int*)alloc(257 * 4);
  int* bucket = (int*)alloc((size_t)EE * 4);

  dim3 blk(256);
  dim3 blk128(128);

  CJobs cj;
  cj.j[0]  = { x,     xb,    512 * 768 };
  cj.j[1]  = { oc_w1, w_oc1, 768 * 768 };
  cj.j[2]  = { oc_w2, w_oc2, 384 * 768 };
  cj.j[3]  = { ip_w1, w_ip1, 384 * 768 };
  cj.j[4]  = { ip_w2, w_ip2, 192 * 384 };
  cj.j[5]  = { rc_w1, w_rc1, 768 * 1536 };
  cj.j[6]  = { rc_w2, w_rc2, 384 * 768 };
  cj.j[7]  = { at_iw, w_aiw, 2304 * 768 };
  cj.j[8]  = { at_ow, w_aow, 768 * 768 };
  for (int l = 0; l < 3; ++l) {
    cj.j[9 + 2 * l]  = { (const float*)d_in[25 + l * 6 + 0], w_gnn[2 * l],     768 * 768 };
    cj.j[10 + 2 * l] = { (const float*)d_in[25 + l * 6 + 2], w_gnn[2 * l + 1], 768 * 768 };
  }
  preamble<<<dim3(128, 18), blk, 0, stream>>>(cj, eidx, estart, bucket, pairs, out_aw);

  const float* bs0 = (const float*)d_in[26];
  const float* bn0 = (const float*)d_in[28];
  const float* gm0 = (const float*)d_in[29];
  const float* bt0 = (const float*)d_in[30];

  // Layer-0 GNN + oc/ip pipeline, width-filled mega launches
  mega1<<<992, blk, 0, stream>>>(xb, w_gnn[0], bs0, selfF, ew, eidx, estart, bucket, aggB,
                                 w_oc1, oc_b1, hA, w_ip1, ip_b1, hI1);
  mega2<<<336, blk, 0, stream>>>(aggB, w_gnn[1], bn0, selfF, oBuf,
                                 hA, w_oc2, oc_b2, hB, hI1, w_ip2, ip_b2, hI2);
  mega3<<<576, blk, 0, stream>>>(oBuf, gm0, bt0, g0,
                                 hB, oc_w3, oc_b3, out_oc, hI2, ip_w3, ip_b3, out_imp);

  // GNN layers 1..2
  const bf16* gcur = g0;
  bf16* gbufs[2] = { g1, g0 };
  for (int l = 1; l < 3; ++l) {
    const float* bs_ = (const float*)d_in[25 + l * 6 + 1];
    const float* bn_ = (const float*)d_in[25 + l * 6 + 3];
    const float* gm_ = (const float*)d_in[25 + l * 6 + 4];
    const float* bt_ = (const float*)d_in[25 + l * 6 + 5];
    gnn_stage1<<<704, blk, 0, stream>>>(gcur, w_gnn[2 * l], bs_, selfF, ew, eidx, estart, bucket, aggB);
    linear_mfma<<<dim3(16, 24), blk128, 0, stream>>>(aggB, w_gnn[2 * l + 1], 768, 0, bn_, selfF, nullptr, oBuf, 768, 768, 1);
    layer_norm<<<512, blk, 0, stream>>>(oBuf, gm_, bt_, gbufs[l & 1]);
    gcur = gbufs[l & 1];
  }

  // attention (mean-over-heads fused via atomics into out_aw)
  linear_mfma<<<dim3(16, 72), blk128, 0, stream>>>(gcur, w_aiw, 768, 0, at_ib, nullptr, qkv, nullptr, 2304, 768, 0);
  attn_kernel<<<dim3(256, 8, 2), blk, 0, stream>>>(qkv, out_aw, ctx);
  linear_mfma<<<dim3(16, 24), blk128, 0, stream>>>(ctx, w_aow, 768, 0, at_ob, nullptr, attB, out_att, 768, 768, 0);

  // relation: A = att@W1a^T + b1, Bv = att@W1b^T (f32 outputs, one launch)
  {
    LinJob a = { attB, w_rc1, 1536, 0,   rc_b1,  nullptr, nullptr, Af, 768, 768, 0, 24 };
    LinJob b = { attB, w_rc1, 1536, 768, nullptr, nullptr, nullptr, Bf, 768, 768, 0, 24 };
    linear_mfma2<<<dim3(16, 24, 2), blk128, 0, stream>>>(a, b);
  }
  // h2 GEMM with fused head -> logit partials; then tiny softmax
  h2_gemm<<<dim3(510, 2), blk, 0, stream>>>(Af, Bf, w_rc2, rc_b2, rc_w3, pairs, logP);
  relsoftmax<<<255, blk, 0, stream>>>(logP, rc_b3, out_rel);
}

// Round 14
// 454.649 us; speedup vs baseline: 1.2299x; 1.0110x over previous
//
#include <hip/hip_runtime.h>
#include <hip/hip_bf16.h>

typedef __bf16 bf16;
typedef __bf16 bf16x4 __attribute__((ext_vector_type(4)));
typedef __bf16 bf16x8 __attribute__((ext_vector_type(8)));
typedef float  f32x4  __attribute__((ext_vector_type(4)));

#define NB 2
#define NN 256
#define DD 768
#define EE 8192
#define NPAIR 32640

__device__ inline float wred_sum(float v) {
#pragma unroll
  for (int o = 32; o > 0; o >>= 1) v += __shfl_down(v, o, 64);
  return v;
}

typedef const __attribute__((address_space(1))) void GASV;
typedef __attribute__((address_space(3))) void LASV;
__device__ __forceinline__ void async_cp16(const void* g, void* l) {
  __builtin_amdgcn_global_load_lds((GASV*)g, (LASV*)l, 16, 0, 0);
}

// ---- preamble: converts + buckets + pairs + out_aw zero, ONE launch ----
struct CJob { const float* s; bf16* d; int n; };
struct CJobs { CJob j[15]; };
__global__ __launch_bounds__(256) void preamble(
    CJobs jobs, const int* __restrict__ eidx, int* __restrict__ estart,
    int* __restrict__ bucket, int2* __restrict__ pairs, float* __restrict__ aw)
{
  int by = blockIdx.y, t = threadIdx.x;
  if (by < 15) {
    const CJob jb = jobs.j[by];
    int nv = jb.n >> 2;
    for (int i = blockIdx.x * 256 + t; i < nv; i += gridDim.x * 256) {
      float4 v = ((const float4*)jb.s)[i];
      bf16x4 pk = { (bf16)v.x, (bf16)v.y, (bf16)v.z, (bf16)v.w };
      *(bf16x4*)(jb.d + 4 * i) = pk;
    }
  } else if (by == 15) {
    if (blockIdx.x != 0) return;
    __shared__ int tg[EE];   // 32 KB
    __shared__ int cnt[256];
    __shared__ int sst[257];
    cnt[t] = 0;
    for (int e = t; e < EE; e += 256) tg[e] = eidx[2 * e + 1];
    __syncthreads();
    for (int e = t; e < EE; e += 256) atomicAdd(&cnt[tg[e]], 1);
    __syncthreads();
    if (t == 0) { int s = 0; for (int i = 0; i < 256; ++i) { sst[i] = s; s += cnt[i]; } sst[256] = s; }
    __syncthreads();
    estart[t] = sst[t];
    if (t == 0) estart[256] = sst[256];
    cnt[t] = sst[t];
    __syncthreads();
    for (int e = t; e < EE; e += 256) {
      int p = atomicAdd(&cnt[tg[e]], 1);
      bucket[p] = e;
    }
  } else if (by == 16) {
#pragma unroll
    for (int u = 0; u < 2; ++u) {
      int i = blockIdx.x + u * 128;
      if (i < 255) {
        int off = i * 255 - (i * (i - 1)) / 2;
        for (int j = i + 1 + t; j < NN; j += 256)
          pairs[off + (j - i - 1)] = make_int2(i, j);
      }
    }
  } else {
    int idx = blockIdx.x * 256 + t;
    ((float4*)aw)[idx] = make_float4(0.f, 0.f, 0.f, 0.f);
  }
}

// GEMM core: one wave computes a 16x32 tile at (m0, n0). lane = tid&63.
__device__ __forceinline__ void lin_core(
    int m0, int n0, const bf16* __restrict__ X, const bf16* __restrict__ W,
    int ldw, int wofs, const float* __restrict__ bias, const float* __restrict__ addF,
    bf16* __restrict__ outB, float* __restrict__ outF, int N, int K, int act)
{
  int lane = threadIdx.x & 63, lr = lane & 15, lq = lane >> 4;
  const bf16* xrow = X + (size_t)(m0 + lr) * K;
  const bf16* wbase = W + (size_t)wofs;
  f32x4 acc[2] = {};
  for (int k = 0; k < K; k += 32) {
    bf16x8 a = *(const bf16x8*)(xrow + k + lq * 8);
    bf16x8 b0 = *(const bf16x8*)(wbase + (size_t)(n0 + lr) * ldw + k + lq * 8);
    bf16x8 b1 = *(const bf16x8*)(wbase + (size_t)(n0 + 16 + lr) * ldw + k + lq * 8);
    acc[0] = __builtin_amdgcn_mfma_f32_16x16x32_bf16(a, b0, acc[0], 0, 0, 0);
    acc[1] = __builtin_amdgcn_mfma_f32_16x16x32_bf16(a, b1, acc[1], 0, 0, 0);
  }
#pragma unroll
  for (int t = 0; t < 2; ++t) {
    int col = n0 + t * 16 + lr;
    float bv = bias ? bias[col] : 0.0f;
#pragma unroll
    for (int r = 0; r < 4; ++r) {
      int row = m0 + lq * 4 + r;
      size_t o = (size_t)row * N + col;
      float v = acc[t][r] + bv;
      if (addF) v += addF[o];
      if (act) v = fmaxf(v, 0.0f);
      if (outB) outB[o] = (bf16)v;
      if (outF) outF[o] = v;
    }
  }
}

// 256-thread (4-wave) M=512 linear section: bid in [0, N/32*8)
__device__ __forceinline__ void lin256(
    int bid, const bf16* X, const bf16* W, int ldw, int wofs,
    const float* bias, const float* addF, bf16* outB, float* outF,
    int N, int K, int act)
{
  int wave = threadIdx.x >> 6;
  lin_core(((bid & 7) * 4 + wave) * 16, (bid >> 3) * 32,
           X, W, ldw, wofs, bias, addF, outB, outF, N, K, act);
}

__global__ __launch_bounds__(128) void linear_mfma(
    const bf16* __restrict__ X, const bf16* __restrict__ W, int ldw, int wofs,
    const float* __restrict__ bias, const float* __restrict__ addF,
    bf16* __restrict__ outB, float* __restrict__ outF,
    int N, int K, int act)
{
  int wave = threadIdx.x >> 6;
  lin_core((blockIdx.x * 2 + wave) * 16, blockIdx.y * 32,
           X, W, ldw, wofs, bias, addF, outB, outF, N, K, act);
}

// Two independent GEMMs in one launch; blockIdx.z picks the job.
struct LinJob {
  const bf16* X; const bf16* W; int ldw; int wofs;
  const float* bias; const float* addF; bf16* outB; float* outF;
  int N, K, act, gy;
};
__global__ __launch_bounds__(128) void linear_mfma2(LinJob j0, LinJob j1)
{
  LinJob j = blockIdx.z ? j1 : j0;
  if ((int)blockIdx.y >= j.gy) return;
  int wave = threadIdx.x >> 6;
  lin_core((blockIdx.x * 2 + wave) * 16, blockIdx.y * 32,
           j.X, j.W, j.ldw, j.wofs, j.bias, j.addF, j.outB, j.outF, j.N, j.K, j.act);
}

// GNN stage-1 body: self-linear (bid 0..191) + edge aggregation (bid 192..703)
__device__ __forceinline__ void gnn_s1_body(
    int bid, const bf16* __restrict__ g, const bf16* __restrict__ ws,
    const float* __restrict__ bs, float* __restrict__ selfF,
    const float* __restrict__ ew, const int* __restrict__ eidx,
    const int* __restrict__ estart, const int* __restrict__ bucket,
    bf16* __restrict__ agg, int* ssrc, float* sw)
{
  int t = threadIdx.x;
  if (bid < 192) {
    lin256(bid, g, ws, 768, 0, bs, nullptr, nullptr, selfF, 768, 768, 0);
    return;
  }
  int e0 = bid - 192;
  int tgt = e0 & 255, b = e0 >> 8;
  int s = estart[tgt], e = estart[tgt + 1];
  s = max(0, min(s, EE));
  e = max(s, min(e, EE));
  const bf16* gb = g + (size_t)b * NN * DD;
  float a0 = 0, a1 = 0, a2 = 0, a3 = 0;
  for (int base = s; base < e; base += 256) {
    int nchunk = min(256, e - base);
    if (t < nchunk) {
      int eid = bucket[base + t];
      eid = max(0, min(eid, EE - 1));
      ssrc[t] = eidx[2 * eid] & (NN - 1);
      sw[t] = ew[eid];
    }
    __syncthreads();
    if (t < 192) {
      for (int q = 0; q < nchunk; ++q) {
        float w = sw[q];
        bf16x4 v = *(const bf16x4*)(gb + (size_t)ssrc[q] * DD + 4 * t);
        a0 += w * (float)v[0]; a1 += w * (float)v[1];
        a2 += w * (float)v[2]; a3 += w * (float)v[3];
      }
    }
    __syncthreads();
  }
  if (t < 192) {
    bf16x4 o = { (bf16)a0, (bf16)a1, (bf16)a2, (bf16)a3 };
    *(bf16x4*)(agg + ((size_t)b * NN + tgt) * DD + 4 * t) = o;
  }
}

__global__ __launch_bounds__(256) void gnn_stage1(
    const bf16* __restrict__ g, const bf16* __restrict__ ws, const float* __restrict__ bs,
    float* __restrict__ selfF,
    const float* __restrict__ ew, const int* __restrict__ eidx,
    const int* __restrict__ estart, const int* __restrict__ bucket, bf16* __restrict__ agg)
{
  __shared__ int   ssrc[256];
  __shared__ float sw[256];
  gnn_s1_body(blockIdx.x, g, ws, bs, selfF, ew, eidx, estart, bucket, agg, ssrc, sw);
}

// MEGA-1: gnn_stage1(l0) [0,704) + oc-L1 [704,896) + ip-L1 [896,992)
__global__ __launch_bounds__(256) void mega1(
    const bf16* __restrict__ xb, const bf16* __restrict__ ws0, const float* __restrict__ bs0,
    float* __restrict__ selfF,
    const float* __restrict__ ew, const int* __restrict__ eidx,
    const int* __restrict__ estart, const int* __restrict__ bucket, bf16* __restrict__ agg,
    const bf16* __restrict__ w_oc1, const float* __restrict__ oc_b1, bf16* __restrict__ hA,
    const bf16* __restrict__ w_ip1, const float* __restrict__ ip_b1, bf16* __restrict__ hI1)
{
  __shared__ int   ssrc[256];
  __shared__ float sw[256];
  int bid = blockIdx.x;
  if (bid < 704)
    gnn_s1_body(bid, xb, ws0, bs0, selfF, ew, eidx, estart, bucket, agg, ssrc, sw);
  else if (bid < 896)
    lin256(bid - 704, xb, w_oc1, 768, 0, oc_b1, nullptr, hA, nullptr, 768, 768, 1);
  else
    lin256(bid - 896, xb, w_ip1, 768, 0, ip_b1, nullptr, hI1, nullptr, 384, 768, 1);
}

// MEGA-2: neigh-linear l0 [0,192) + oc-L2 [192,288) + ip-L2 [288,336)
__global__ __launch_bounds__(256) void mega2(
    const bf16* __restrict__ aggB, const bf16* __restrict__ wn0, const float* __restrict__ bn0,
    const float* __restrict__ selfF, float* __restrict__ oBuf,
    const bf16* __restrict__ hA, const bf16* __restrict__ w_oc2, const float* __restrict__ oc_b2,
    bf16* __restrict__ hB,
    const bf16* __restrict__ hI1, const bf16* __restrict__ w_ip2, const float* __restrict__ ip_b2,
    bf16* __restrict__ hI2)
{
  int bid = blockIdx.x;
  if (bid < 192)
    lin256(bid, aggB, wn0, 768, 0, bn0, selfF, nullptr, oBuf, 768, 768, 1);
  else if (bid < 288)
    lin256(bid - 192, hA, w_oc2, 768, 0, oc_b2, nullptr, hB, nullptr, 384, 768, 1);
  else
    lin256(bid - 288, hI1, w_ip2, 384, 0, ip_b2, nullptr, hI2, nullptr, 192, 384, 1);
}

// LayerNorm body (one row per block-slot)
__device__ __forceinline__ void ln_body(
    int row, const float* __restrict__ o, const float* __restrict__ gm,
    const float* __restrict__ bt, bf16* __restrict__ gout, float* red)
{
  int t = threadIdx.x;
  const float* orow = o + (size_t)row * DD;
  float v0 = orow[t], v1 = orow[t + 256], v2 = orow[t + 512];
  float s = v0 + v1 + v2;
  float q = v0 * v0 + v1 * v1 + v2 * v2;
  float ws_ = wred_sum(s), wq = wred_sum(q);
  if ((t & 63) == 0) { red[t >> 6] = ws_; red[4 + (t >> 6)] = wq; }
  __syncthreads();
  float S = red[0] + red[1] + red[2] + red[3];
  float Q = red[4] + red[5] + red[6] + red[7];
  float mu = S * (1.0f / 768.0f);
  float var = Q * (1.0f / 768.0f) - mu * mu;
  float rstd = rsqrtf(var + 1e-5f);
  bf16* gr = gout + (size_t)row * DD;
  gr[t]       = (bf16)(gm[t]       * (v0 - mu) * rstd + bt[t]);
  gr[t + 256] = (bf16)(gm[t + 256] * (v1 - mu) * rstd + bt[t + 256]);
  gr[t + 512] = (bf16)(gm[t + 512] * (v2 - mu) * rstd + bt[t + 512]);
}

__global__ __launch_bounds__(256) void layer_norm(
    const float* __restrict__ o, const float* __restrict__ gm,
    const float* __restrict__ bt, bf16* __restrict__ gout)
{
  __shared__ float red[8];
  ln_body(blockIdx.x, o, gm, bt, gout, red);
}

// MEGA-3: LN l0 [0,512) + oc softmax head [512,544) + ip sigmoid head [544,576)
__global__ __launch_bounds__(256) void mega3(
    const float* __restrict__ oBuf, const float* __restrict__ gm0,
    const float* __restrict__ bt0, bf16* __restrict__ gout,
    const bf16* __restrict__ hOC, const float* __restrict__ w3, const float* __restrict__ b3,
    float* __restrict__ outOC,
    const bf16* __restrict__ hIP, const float* __restrict__ w1, const float* __restrict__ b1,
    float* __restrict__ outIP)
{
  __shared__ float sh[3072];
  int bid = blockIdx.x, t = threadIdx.x;
  int wave = t >> 6, lane = t & 63;
  if (bid < 512) {
    ln_body(bid, oBuf, gm0, bt0, gout, sh);
  } else if (bid < 544) {
    for (int i = t; i < 8 * 384; i += 256) sh[i] = w3[i];
    __syncthreads();
    int k0 = lane * 6;
#pragma unroll
    for (int i = 0; i < 4; ++i) {
      int r = (bid - 512) * 16 + wave * 4 + i;
      const bf16* hr = hOC + (size_t)r * 384;
      float hv[6];
#pragma unroll
      for (int j = 0; j < 6; ++j) hv[j] = (float)hr[k0 + j];
      float lg[8];
#pragma unroll
      for (int c = 0; c < 8; ++c) {
        float p = 0;
#pragma unroll
        for (int j = 0; j < 6; ++j) p += hv[j] * sh[c * 384 + k0 + j];
        lg[c] = wred_sum(p);
      }
      if (lane == 0) {
        float mx = lg[0] + b3[0];
#pragma unroll
        for (int c = 0; c < 8; ++c) { lg[c] += b3[c]; mx = fmaxf(mx, lg[c]); }
        float ex[8], sum = 0;
#pragma unroll
        for (int c = 0; c < 8; ++c) { ex[c] = expf(lg[c] - mx); sum += ex[c]; }
        float inv = 1.0f / sum;
#pragma unroll
        for (int c = 0; c < 8; ++c) outOC[(size_t)r * 8 + c] = ex[c] * inv;
      }
    }
  } else {
    if (t < 192) sh[t] = w1[t];
    __syncthreads();
    int k0 = lane * 3;
#pragma unroll
    for (int i = 0; i < 4; ++i) {
      int r = (bid - 544) * 16 + wave * 4 + i;
      const bf16* hr = hIP + (size_t)r * 192;
      float p = (float)hr[k0] * sh[k0] + (float)hr[k0 + 1] * sh[k0 + 1]
              + (float)hr[k0 + 2] * sh[k0 + 2];
      float s = wred_sum(p);
      if (lane == 0) outIP[r] = 1.0f / (1.0f + expf(-(s + b1[0])));
    }
  }
}

// grid (q=256, h=8, b=2); one block per (b,h,q) row.
__global__ __launch_bounds__(256) void attn_kernel(
    const bf16* __restrict__ qkv, float* __restrict__ aw, bf16* __restrict__ ctx)
{
  __shared__ float qs[96];
  __shared__ float ps[256];
  __shared__ float part[192];
  __shared__ float red[8];
  int qi = blockIdx.x, h = blockIdx.y, b = blockIdx.z, t = threadIdx.x;
  const bf16* qrow = qkv + ((size_t)(b * NN + qi)) * 2304 + h * 96;
  if (t < 96) qs[t] = (float)qrow[t];
  __syncthreads();
  const bf16* krow = qkv + ((size_t)(b * NN + t)) * 2304 + 768 + h * 96;
  float s = 0;
#pragma unroll
  for (int i = 0; i < 12; ++i) {
    bf16x8 kv = *(const bf16x8*)(krow + 8 * i);
#pragma unroll
    for (int j = 0; j < 8; ++j) s += qs[8 * i + j] * (float)kv[j];
  }
  s *= 0.10206207261596577f; // 1/sqrt(96)
  float wm = s;
#pragma unroll
  for (int o = 32; o > 0; o >>= 1) wm = fmaxf(wm, __shfl_down(wm, o, 64));
  if ((t & 63) == 0) red[t >> 6] = wm;
  __syncthreads();
  float MX = fmaxf(fmaxf(red[0], red[1]), fmaxf(red[2], red[3]));
  float e = expf(s - MX);
  float wsum = wred_sum(e);
  if ((t & 63) == 0) red[4 + (t >> 6)] = wsum;
  __syncthreads();
  float SUM = red[4] + red[5] + red[6] + red[7];
  float p = e / SUM;
  ps[t] = p;
  atomicAdd(&aw[((size_t)(b * NN + qi)) * NN + t], p * 0.125f);
  __syncthreads();
  if (t < 192) {
    int d = t % 96, half = t / 96;
    const bf16* vbase = qkv + (size_t)b * NN * 2304 + 1536 + h * 96 + d;
    float a0 = 0, a1 = 0, a2 = 0, a3 = 0;
    int k0 = half * 128;
    for (int k = k0; k < k0 + 128; k += 4) {
      a0 += ps[k]     * (float)vbase[(size_t)k * 2304];
      a1 += ps[k + 1] * (float)vbase[(size_t)(k + 1) * 2304];
      a2 += ps[k + 2] * (float)vbase[(size_t)(k + 2) * 2304];
      a3 += ps[k + 3] * (float)vbase[(size_t)(k + 3) * 2304];
    }
    part[t] = (a0 + a1) + (a2 + a3);
  }
  __syncthreads();
  if (t < 96)
    ctx[((size_t)(b * NN + qi)) * DD + h * 96 + t] = (bf16)(part[t] + part[t + 96]);
}

// Relation hidden GEMM + FUSED head partials. bf16 Af/Bf (R12 config:
// measured 80.4us; R13's f32 variant regressed to 98us — gen-phase is
// load-bound, f32 doubled its bytes).
__global__ __launch_bounds__(256) void h2_gemm(
    const bf16* __restrict__ Af, const bf16* __restrict__ Bf,
    const bf16* __restrict__ w2, const float* __restrict__ b2,
    const float* __restrict__ w3, const int2* __restrict__ pairs,
    float* __restrict__ logP)
{
  __shared__ bf16x8 sh1[512];   // 8 KB  (128 rows x 4 planes)
  __shared__ bf16x8 sw2[768];   // 12 KB (192 rows x 4 planes)
  __shared__ int rA[128], rB[128];
  int tid = threadIdx.x;
  int r0 = blockIdx.x * 128;
  int bb = (r0 >= NPAIR) ? 1 : 0;   // tiles never straddle batches (32640%128==0)
  int n0 = blockIdx.y * 192;
  if (tid < 128) {
    int2 ij = pairs[r0 - bb * NPAIR + tid];
    rA[tid] = (bb * NN + ij.x) * DD;
    rB[tid] = (bb * NN + ij.y) * DD;
  }
  __syncthreads();
  int hrow = tid >> 1, hp = (tid & 1) * 2;
  const bf16* ar = Af + rA[hrow] + hp * 8;
  const bf16* br = Bf + rB[hrow] + hp * 8;
  int hslot = ((hrow >> 4) << 6) + (hp << 4) + (hrow & 15);
  int srow[3], spl[3];
#pragma unroll
  for (int q = 0; q < 3; ++q) {
    int a = q * 256 + tid;
    srow[q] = ((a >> 6) << 4) + (a & 15);
    spl[q] = (a >> 4) & 3;
  }
  int wave = tid >> 6, lane = tid & 63, lr = lane & 15, lq = lane >> 4;
  int wr = wave >> 1, wc = wave & 1;
  f32x4 acc[4][6] = {};
  for (int k0 = 0; k0 < 768; k0 += 32) {
#pragma unroll
    for (int q = 0; q < 3; ++q)
      async_cp16(w2 + (size_t)(n0 + srow[q]) * 768 + k0 + spl[q] * 8,
                 (char*)sw2 + (q * 256 + tid) * 16);
    bf16x8 a0 = *(const bf16x8*)(ar + k0);
    bf16x8 a1 = *(const bf16x8*)(ar + k0 + 8);
    bf16x8 b0 = *(const bf16x8*)(br + k0);
    bf16x8 b1 = *(const bf16x8*)(br + k0 + 8);
    bf16x8 h0, h1v;
#pragma unroll
    for (int j = 0; j < 8; ++j) {
      h0[j]  = (bf16)fmaxf((float)a0[j] + (float)b0[j], 0.f);
      h1v[j] = (bf16)fmaxf((float)a1[j] + (float)b1[j], 0.f);
    }
    sh1[hslot] = h0;
    sh1[hslot + 16] = h1v;
    __syncthreads();
    bf16x8 af[4], bfr[6];
#pragma unroll
    for (int rf = 0; rf < 4; ++rf)
      af[rf] = sh1[(wr * 4 + rf) * 64 + lq * 16 + lr];
#pragma unroll
    for (int cf = 0; cf < 6; ++cf)
      bfr[cf] = sw2[(wc * 6 + cf) * 64 + lq * 16 + lr];
#pragma unroll
    for (int rf = 0; rf < 4; ++rf)
#pragma unroll
      for (int cf = 0; cf < 6; ++cf)
        acc[rf][cf] = __builtin_amdgcn_mfma_f32_16x16x32_bf16(af[rf], bfr[cf], acc[rf][cf], 0, 0, 0);
    __syncthreads();   // also frees sh1/sw2 for epilogue reuse on last iter
  }
  // ---- fused relation head ----
  char* zone = (wave < 2) ? ((char*)sw2 + wave * 3328)
                          : ((char*)sh1 + (wave - 2) * 3328);
  bf16x8 w3f[3];
#pragma unroll
  for (int ks = 0; ks < 3; ++ks) {
    bf16x8 f = {};
    if (lr < 8) {
      const float* wsrc = w3 + lr * 384 + n0 + wc * 96 + ks * 32 + lq * 8;
#pragma unroll
      for (int j = 0; j < 8; ++j) f[j] = (bf16)wsrc[j];
    }
    w3f[ks] = f;
  }
  float* lp = logP + (size_t)((n0 >= 192 ? 2 : 0) + wc) * 65280 * 8;
  bf16* zb = (bf16*)zone;
#pragma unroll
  for (int rf = 0; rf < 4; ++rf) {
#pragma unroll
    for (int cf = 0; cf < 6; ++cf) {
      int col = n0 + wc * 96 + cf * 16 + lr;
      float bv2 = b2[col];
#pragma unroll
      for (int r = 0; r < 4; ++r)
        zb[(lq * 4 + r) * 104 + cf * 16 + lr] = (bf16)fmaxf(acc[rf][cf][r] + bv2, 0.f);
    }
    f32x4 lacc = {};
#pragma unroll
    for (int ks = 0; ks < 3; ++ks) {
      bf16x8 afr = *(const bf16x8*)(zone + lr * 208 + ks * 64 + lq * 16);
      lacc = __builtin_amdgcn_mfma_f32_16x16x32_bf16(afr, w3f[ks], lacc, 0, 0, 0);
    }
    if (lr < 8) {
#pragma unroll
      for (int r = 0; r < 4; ++r) {
        int grow = r0 + wr * 64 + rf * 16 + lq * 4 + r;
        lp[(size_t)grow * 8 + lr] = lacc[r];
      }
    }
  }
}

// Sum 4 logit partials + bias, softmax, write out_rel. Thread = one pair-row.
__global__ __launch_bounds__(256) void relsoftmax(
    const float* __restrict__ logP, const float* __restrict__ b3,
    float* __restrict__ out)
{
  int row = blockIdx.x * 256 + threadIdx.x;   // grid 255*256 = 65280
  float lg[8];
#pragma unroll
  for (int c = 0; c < 8; ++c) lg[c] = b3[c];
#pragma unroll
  for (int p = 0; p < 4; ++p) {
    const float* lp = logP + ((size_t)p * 65280 + row) * 8;
#pragma unroll
    for (int c = 0; c < 8; ++c) lg[c] += lp[c];
  }
  float mx = lg[0];
#pragma unroll
  for (int c = 1; c < 8; ++c) mx = fmaxf(mx, lg[c]);
  float ex[8], sum = 0;
#pragma unroll
  for (int c = 0; c < 8; ++c) { ex[c] = expf(lg[c] - mx); sum += ex[c]; }
  float inv = 1.0f / sum;
#pragma unroll
  for (int c = 0; c < 8; ++c) out[(size_t)row * 8 + c] = ex[c] * inv;
}

extern "C" void kernel_launch(void* const* d_in, const int* in_sizes, int n_in,
                              void* d_out, int out_size, void* d_ws, size_t ws_size,
                              hipStream_t stream)
{
  (void)in_sizes; (void)n_in; (void)out_size; (void)ws_size;
  const float* x    = (const float*)d_in[0];
  const float* ew   = (const float*)d_in[1];
  const int*   eidx = (const int*)d_in[2];
  const float* oc_w1 = (const float*)d_in[3];  const float* oc_b1 = (const float*)d_in[4];
  const float* oc_w2 = (const float*)d_in[5];  const float* oc_b2 = (const float*)d_in[6];
  const float* oc_w3 = (const float*)d_in[7];  const float* oc_b3 = (const float*)d_in[8];
  const float* ip_w1 = (const float*)d_in[9];  const float* ip_b1 = (const float*)d_in[10];
  const float* ip_w2 = (const float*)d_in[11]; const float* ip_b2 = (const float*)d_in[12];
  const float* ip_w3 = (const float*)d_in[13]; const float* ip_b3 = (const float*)d_in[14];
  const float* rc_w1 = (const float*)d_in[15]; const float* rc_b1 = (const float*)d_in[16];
  const float* rc_w2 = (const float*)d_in[17]; const float* rc_b2 = (const float*)d_in[18];
  const float* rc_w3 = (const float*)d_in[19]; const float* rc_b3 = (const float*)d_in[20];
  const float* at_iw = (const float*)d_in[21]; const float* at_ib = (const float*)d_in[22];
  const float* at_ow = (const float*)d_in[23]; const float* at_ob = (const float*)d_in[24];

  float* out = (float*)d_out;
  float* out_oc  = out;            // [2,256,8]
  float* out_rel = out + 4096;     // [2,32640,8]
  float* out_imp = out + 526336;   // [2,256,1]
  float* out_att = out + 526848;   // [2,256,768]
  float* out_aw  = out + 920064;   // [2,256,256]

  char* wp = (char*)d_ws;
  auto alloc = [&](size_t bytes) { char* p = wp; wp += (bytes + 255) & ~(size_t)255; return p; };
  float* logP  = (float*)alloc((size_t)4 * 65280 * 8 * 4);    // 8.4 MB
  float* selfF = (float*)alloc((size_t)512 * 768 * 4);
  float* oBuf  = (float*)alloc((size_t)512 * 768 * 4);
  bf16* AfB  = (bf16*)alloc((size_t)512 * 768 * 2);
  bf16* BfB  = (bf16*)alloc((size_t)512 * 768 * 2);
  bf16* xb   = (bf16*)alloc((size_t)512 * 768 * 2);
  bf16* g0   = (bf16*)alloc((size_t)512 * 768 * 2);
  bf16* g1   = (bf16*)alloc((size_t)512 * 768 * 2);
  bf16* hA   = (bf16*)alloc((size_t)512 * 768 * 2);
  bf16* hB   = (bf16*)alloc((size_t)512 * 384 * 2);
  bf16* hI1  = (bf16*)alloc((size_t)512 * 384 * 2);
  bf16* hI2  = (bf16*)alloc((size_t)512 * 192 * 2);
  bf16* aggB = (bf16*)alloc((size_t)512 * 768 * 2);
  bf16* qkv  = (bf16*)alloc((size_t)512 * 2304 * 2);
  bf16* ctx  = (bf16*)alloc((size_t)512 * 768 * 2);
  bf16* attB = (bf16*)alloc((size_t)512 * 768 * 2);
  bf16* w_oc1 = (bf16*)alloc((size_t)768 * 768 * 2);
  bf16* w_oc2 = (bf16*)alloc((size_t)384 * 768 * 2);
  bf16* w_ip1 = (bf16*)alloc((size_t)384 * 768 * 2);
  bf16* w_ip2 = (bf16*)alloc((size_t)192 * 384 * 2);
  bf16* w_rc1 = (bf16*)alloc((size_t)768 * 1536 * 2);
  bf16* w_rc2 = (bf16*)alloc((size_t)384 * 768 * 2);
  bf16* w_aiw = (bf16*)alloc((size_t)2304 * 768 * 2);
  bf16* w_aow = (bf16*)alloc((size_t)768 * 768 * 2);
  bf16* w_gnn[6];
  for (int i = 0; i < 6; ++i) w_gnn[i] = (bf16*)alloc((size_t)768 * 768 * 2);
  int2* pairs = (int2*)alloc((size_t)NPAIR * 8);
  int* estart = (int*)alloc(257 * 4);
  int* bucket = (int*)alloc((size_t)EE * 4);

  dim3 blk(256);
  dim3 blk128(128);

  CJobs cj;
  cj.j[0]  = { x,     xb,    512 * 768 };
  cj.j[1]  = { oc_w1, w_oc1, 768 * 768 };
  cj.j[2]  = { oc_w2, w_oc2, 384 * 768 };
  cj.j[3]  = { ip_w1, w_ip1, 384 * 768 };
  cj.j[4]  = { ip_w2, w_ip2, 192 * 384 };
  cj.j[5]  = { rc_w1, w_rc1, 768 * 1536 };
  cj.j[6]  = { rc_w2, w_rc2, 384 * 768 };
  cj.j[7]  = { at_iw, w_aiw, 2304 * 768 };
  cj.j[8]  = { at_ow, w_aow, 768 * 768 };
  for (int l = 0; l < 3; ++l) {
    cj.j[9 + 2 * l]  = { (const float*)d_in[25 + l * 6 + 0], w_gnn[2 * l],     768 * 768 };
    cj.j[10 + 2 * l] = { (const float*)d_in[25 + l * 6 + 2], w_gnn[2 * l + 1], 768 * 768 };
  }
  preamble<<<dim3(128, 18), blk, 0, stream>>>(cj, eidx, estart, bucket, pairs, out_aw);

  const float* bs0 = (const float*)d_in[26];
  const float* bn0 = (const float*)d_in[28];
  const float* gm0 = (const float*)d_in[29];
  const float* bt0 = (const float*)d_in[30];

  // Layer-0 GNN + oc/ip pipeline, width-filled mega launches
  mega1<<<992, blk, 0, stream>>>(xb, w_gnn[0], bs0, selfF, ew, eidx, estart, bucket, aggB,
                                 w_oc1, oc_b1, hA, w_ip1, ip_b1, hI1);
  mega2<<<336, blk, 0, stream>>>(aggB, w_gnn[1], bn0, selfF, oBuf,
                                 hA, w_oc2, oc_b2, hB, hI1, w_ip2, ip_b2, hI2);
  mega3<<<576, blk, 0, stream>>>(oBuf, gm0, bt0, g0,
                                 hB, oc_w3, oc_b3, out_oc, hI2, ip_w3, ip_b3, out_imp);

  // GNN layers 1..2
  const bf16* gcur = g0;
  bf16* gbufs[2] = { g1, g0 };
  for (int l = 1; l < 3; ++l) {
    const float* bs_ = (const float*)d_in[25 + l * 6 + 1];
    const float* bn_ = (const float*)d_in[25 + l * 6 + 3];
    const float* gm_ = (const float*)d_in[25 + l * 6 + 4];
    const float* bt_ = (const float*)d_in[25 + l * 6 + 5];
    gnn_stage1<<<704, blk, 0, stream>>>(gcur, w_gnn[2 * l], bs_, selfF, ew, eidx, estart, bucket, aggB);
    linear_mfma<<<dim3(16, 24), blk128, 0, stream>>>(aggB, w_gnn[2 * l + 1], 768, 0, bn_, selfF, nullptr, oBuf, 768, 768, 1);
    layer_norm<<<512, blk, 0, stream>>>(oBuf, gm_, bt_, gbufs[l & 1]);
    gcur = gbufs[l & 1];
  }

  // attention (mean-over-heads fused via atomics into out_aw)
  linear_mfma<<<dim3(16, 72), blk128, 0, stream>>>(gcur, w_aiw, 768, 0, at_ib, nullptr, qkv, nullptr, 2304, 768, 0);
  attn_kernel<<<dim3(256, 8, 2), blk, 0, stream>>>(qkv, out_aw, ctx);
  linear_mfma<<<dim3(16, 24), blk128, 0, stream>>>(ctx, w_aow, 768, 0, at_ob, nullptr, attB, out_att, 768, 768, 0);

  // relation: A = att@W1a^T + b1, Bv = att@W1b^T (bf16 outputs, one launch)
  {
    LinJob a = { attB, w_rc1, 1536, 0,   rc_b1,  nullptr, AfB, nullptr, 768, 768, 0, 24 };
    LinJob b = { attB, w_rc1, 1536, 768, nullptr, nullptr, BfB, nullptr, 768, 768, 0, 24 };
    linear_mfma2<<<dim3(16, 24, 2), blk128, 0, stream>>>(a, b);
  }
  // h2 GEMM with fused head -> logit partials; then tiny softmax
  h2_gemm<<<dim3(510, 2), blk, 0, stream>>>(AfB, BfB, w_rc2, rc_b2, rc_w3, pairs, logP);
  relsoftmax<<<255, blk, 0, stream>>>(logP, rc_b3, out_rel);
}